// Round 1
// baseline (1968.152 us; speedup 1.0000x reference)
//
#include <hip/hip_runtime.h>

// ---------- types & helpers ----------
typedef short short8 __attribute__((ext_vector_type(8)));
typedef __bf16 bf16x8 __attribute__((ext_vector_type(8)));
typedef float f32x4 __attribute__((ext_vector_type(4)));

#define DEVI __device__ __forceinline__

DEVI float bf2f(short s) {
  unsigned u = ((unsigned)(unsigned short)s) << 16;
  return __builtin_bit_cast(float, u);
}
DEVI short f2bf(float f) {
  unsigned u = __builtin_bit_cast(unsigned, f);
  u = (u + 0x7fffu + ((u >> 16) & 1u)) >> 16;
  return (short)u;
}
DEVI f32x4 mfma16(short8 a, short8 b, f32x4 c) {
  return __builtin_amdgcn_mfma_f32_16x16x32_bf16(
      __builtin_bit_cast(bf16x8, a), __builtin_bit_cast(bf16x8, b), c, 0, 0, 0);
}

// ---------- weight prep: bf16 casts + folded W'' = [w1a | w1b - w1a] ----------
__global__ __launch_bounds__(256) void prep_kernel(
    const float* __restrict__ w2, const float* __restrict__ s1w2,
    const float* __restrict__ s2w2, const float* __restrict__ s1w1,
    const float* __restrict__ s2w1, short* __restrict__ w2b,
    short* __restrict__ s1w2b, short* __restrict__ s2w2b,
    short* __restrict__ W1pp, short* __restrict__ W2pp) {
  int i = blockIdx.x * 256 + threadIdx.x;
  if (i < 4096) {
    w2b[i] = f2bf(w2[i]);
  } else if (i < 20480) {
    int j = i - 4096; s1w2b[j] = f2bf(s1w2[j]);
  } else if (i < 86016) {
    int j = i - 20480; s2w2b[j] = f2bf(s2w2[j]);
  } else if (i < 102400) {
    int j = i - 86016; int c = j & 127;
    float v = s1w1[j]; if (c >= 64) v -= s1w1[j - 64];
    W1pp[j] = f2bf(v);
  } else if (i < 167936) {
    int j = i - 102400; int c = j & 255;
    float v = s2w1[j]; if (c >= 128) v -= s2w1[j - 128];
    W2pp[j] = f2bf(v);
  }
}

// ---------- stage A: xyz transpose + h0 = x @ w1^T (K=3, VALU fp32) ----------
__global__ __launch_bounds__(256) void stageA_kernel(
    const float* __restrict__ x, const float* __restrict__ w1,
    float* __restrict__ xyz, short* __restrict__ h0) {
  int i = blockIdx.x * 256 + threadIdx.x;  // b*4096 + n, < 131072
  int b = i >> 12, n = i & 4095;
  const float* xb = x + ((size_t)b * 3 << 12) + n;
  float x0 = xb[0], x1 = xb[4096], x2 = xb[8192];
  float* xp = xyz + (size_t)i * 3;
  xp[0] = x0; xp[1] = x1; xp[2] = x2;
  short* hp = h0 + ((size_t)i << 6);
#pragma unroll
  for (int o8 = 0; o8 < 8; ++o8) {
    short8 t;
#pragma unroll
    for (int j = 0; j < 8; ++j) {
      int o = o8 * 8 + j;
      float h = x0 * w1[o * 3] + x1 * w1[o * 3 + 1] + x2 * w1[o * 3 + 2];
      t[j] = f2bf(h);
    }
    *reinterpret_cast<short8*>(hp + o8 * 8) = t;
  }
}

// ---------- channel stats for a [M][64] bf16 tensor -> transposed partials ----------
__global__ __launch_bounds__(256) void stats64_kernel(
    const short* __restrict__ h, float* __restrict__ partials, int M) {
  __shared__ float l0[256], l1[256];
  const int tid = threadIdx.x;
  const int c = tid & 63, g = tid >> 6;
  float s0 = 0.f, s1 = 0.f;
  for (int m = blockIdx.x * 4 + g; m < M; m += gridDim.x * 4) {
    float v = bf2f(h[(size_t)m * 64 + c]);
    s0 += v; s1 += v * v;
  }
  l0[tid] = s0; l1[tid] = s1;
  __syncthreads();
  if (g == 0) {
    for (int w = 1; w < 4; ++w) { s0 += l0[c + w * 64]; s1 += l1[c + w * 64]; }
    partials[(size_t)c * gridDim.x + blockIdx.x] = s0;
    partials[(size_t)(64 + c) * gridDim.x + blockIdx.x] = s1;
  }
}

// ---------- reduce partials[j][0..NB) -> totals[j] ----------
__global__ __launch_bounds__(256) void reduce_kernel(
    const float* __restrict__ partials, float* __restrict__ totals, int NB) {
  __shared__ float l[4];
  const int j = blockIdx.x, tid = threadIdx.x;
  float s = 0.f;
  for (int i = tid; i < NB; i += 256) s += partials[(size_t)j * NB + i];
#pragma unroll
  for (int off = 1; off < 64; off <<= 1) s += __shfl_xor(s, off);
  if ((tid & 63) == 0) l[tid >> 6] = s;
  __syncthreads();
  if (tid == 0) totals[j] = l[0] + l[1] + l[2] + l[3];
}

// ---------- finalize BN: scale = g*rsqrt(var+eps), shift = b - mean*scale ----------
__global__ void finalize_kernel(const float* __restrict__ totals,
                                const float* __restrict__ gamma,
                                const float* __restrict__ beta,
                                float* __restrict__ scale, float* __restrict__ shift,
                                int C, float invM) {
  int c = threadIdx.x;
  if (c < C) {
    float mean = totals[c] * invM;
    float var = totals[C + c] * invM - mean * mean;
    var = fmaxf(var, 0.f);
    float sc = gamma[c] / sqrtf(var + 1e-5f);
    scale[c] = sc;
    shift[c] = beta[c] - mean * sc;
  }
}

// ---------- elementwise BN+ReLU apply (bf16 -> bf16), 8 elems/thread ----------
__global__ __launch_bounds__(256) void apply_kernel(
    const short* __restrict__ h, short* __restrict__ f,
    const float* __restrict__ scale, const float* __restrict__ shift,
    int total8, int Cmask) {
  int t = blockIdx.x * 256 + threadIdx.x;
  if (t >= total8) return;
  size_t i = (size_t)t * 8;
  int c0 = (int)(i & (size_t)Cmask);
  short8 v = *reinterpret_cast<const short8*>(h + i);
  short8 o;
#pragma unroll
  for (int j = 0; j < 8; ++j) {
    float y = bf2f(v[j]) * scale[c0 + j] + shift[c0 + j];
    o[j] = f2bf(fmaxf(y, 0.f));
  }
  *reinterpret_cast<short8*>(f + i) = o;
}

// ---------- farthest point sampling; exact match to reference scan ----------
template <int NPTS, int NSEL>
__global__ __launch_bounds__(256) void fps_kernel(const float* __restrict__ xyz,
                                                  int* __restrict__ out) {
  constexpr int PT = NPTS / 256;
  __shared__ float sx[NPTS], sy[NPTS], sz[NPTS];
  __shared__ float wv[4];
  __shared__ int wi[4];
  const int tid = threadIdx.x, b = blockIdx.x;
  const float* base = xyz + (size_t)b * NPTS * 3;
  float px[PT], py[PT], pz[PT], dmin[PT];
#pragma unroll
  for (int j = 0; j < PT; ++j) {
    int n = j * 256 + tid;
    px[j] = base[n * 3]; py[j] = base[n * 3 + 1]; pz[j] = base[n * 3 + 2];
    sx[n] = px[j]; sy[n] = py[j]; sz[n] = pz[j];
    dmin[j] = 1e10f;
  }
  __syncthreads();
  int far = 0;
  for (int it = 0; it < NSEL; ++it) {
    if (tid == 0) out[b * NSEL + it] = far;
    float cx = sx[far], cy = sy[far], cz = sz[far];
    float bv = -1.f; int bi = 0x7fffffff;
#pragma unroll
    for (int j = 0; j < PT; ++j) {
      float dx = __fsub_rn(px[j], cx), dy = __fsub_rn(py[j], cy), dz = __fsub_rn(pz[j], cz);
      float d = __fadd_rn(__fadd_rn(__fmul_rn(dx, dx), __fmul_rn(dy, dy)), __fmul_rn(dz, dz));
      float dm = fminf(dmin[j], d);
      dmin[j] = dm;
      if (dm > bv) { bv = dm; bi = j * 256 + tid; }  // strict > keeps smallest n locally
    }
#pragma unroll
    for (int off = 1; off < 64; off <<= 1) {
      float ov = __shfl_xor(bv, off); int oi = __shfl_xor(bi, off);
      if (ov > bv || (ov == bv && oi < bi)) { bv = ov; bi = oi; }
    }
    if ((tid & 63) == 0) { wv[tid >> 6] = bv; wi[tid >> 6] = bi; }
    __syncthreads();
    bv = wv[0]; bi = wi[0];
#pragma unroll
    for (int w = 1; w < 4; ++w) {
      float ov = wv[w]; int oi = wi[w];
      if (ov > bv || (ov == bv && oi < bi)) { bv = ov; bi = oi; }
    }
    far = bi;
    __syncthreads();
  }
}

// ---------- kNN: 32 smallest (d, idx) per center; distances unfused fp32 ----------
template <int NPTS, int S>
__global__ __launch_bounds__(256) void knn_kernel(const float* __restrict__ pts,
                                                  const float* __restrict__ ctr,
                                                  int* __restrict__ knn) {
  constexpr int PT = NPTS / 256;
  __shared__ float wv[4];
  __shared__ int wi[4];
  const int tid = threadIdx.x, bs = blockIdx.x;
  const int b = bs / S;
  const float* base = pts + (size_t)b * NPTS * 3;
  const float qx = ctr[bs * 3], qy = ctr[bs * 3 + 1], qz = ctr[bs * 3 + 2];
  const float qq = __fadd_rn(__fadd_rn(__fmul_rn(qx, qx), __fmul_rn(qy, qy)), __fmul_rn(qz, qz));
  float d[PT];
#pragma unroll
  for (int j = 0; j < PT; ++j) {
    int n = j * 256 + tid;
    float x = base[n * 3], y = base[n * 3 + 1], z = base[n * 3 + 2];
    float pp = __fadd_rn(__fadd_rn(__fmul_rn(x, x), __fmul_rn(y, y)), __fmul_rn(z, z));
    float dot = __fadd_rn(__fadd_rn(__fmul_rn(qx, x), __fmul_rn(qy, y)), __fmul_rn(qz, z));
    d[j] = __fsub_rn(__fadd_rn(qq, pp), __fmul_rn(2.f, dot));
  }
  unsigned sel = 0;
  for (int k = 0; k < 32; ++k) {
    float bv = 3.4e38f; int bi = 0x7fffffff;
#pragma unroll
    for (int j = 0; j < PT; ++j) {
      if (!((sel >> j) & 1u)) {
        if (d[j] < bv) { bv = d[j]; bi = j * 256 + tid; }
      }
    }
#pragma unroll
    for (int off = 1; off < 64; off <<= 1) {
      float ov = __shfl_xor(bv, off); int oi = __shfl_xor(bi, off);
      if (ov < bv || (ov == bv && oi < bi)) { bv = ov; bi = oi; }
    }
    if ((tid & 63) == 0) { wv[tid >> 6] = bv; wi[tid >> 6] = bi; }
    __syncthreads();
    bv = wv[0]; bi = wi[0];
#pragma unroll
    for (int w = 1; w < 4; ++w) {
      float ov = wv[w]; int oi = wi[w];
      if (ov < bv || (ov == bv && oi < bi)) { bv = ov; bi = oi; }
    }
    if (tid == 0) knn[(size_t)bs * 32 + k] = bi;
    if ((bi & 255) == tid) sel |= 1u << (bi >> 8);
    __syncthreads();
  }
}

// ---------- gather centers: xyz + features at fps indices ----------
template <int S, int NPTS, int C>
__global__ void gather_kernel(const int* __restrict__ fps, const float* __restrict__ xyzsrc,
                              const short* __restrict__ fsrc, float* __restrict__ xyzdst,
                              short* __restrict__ fdst) {
  const int bs = blockIdx.x, tid = threadIdx.x;
  const int b = bs / S;
  const int idx = fps[bs];
  fdst[(size_t)bs * C + tid] = fsrc[((size_t)b * NPTS + idx) * C + tid];
  if (tid < 3) xyzdst[(size_t)bs * 3 + tid] = xyzsrc[((size_t)b * NPTS + idx) * 3 + tid];
}

// ---------- MFMA GEMM: [M][KD] @ [ND][KD]^T -> [M][ND] bf16 + BN partials
// GATHER: A-row m=(b,s,k): first KD/2 from F[b, knn[m], :], second from FC[b, s, :]
// BNA: apply scale/shift + ReLU to A elements on load (bf16 in/out)
template <int KD, int ND, bool GATHER, bool BNA, int NPTS, int S>
__global__ __launch_bounds__(256) void gemm_kernel(
    const short* A, const short* FC, const int* KNNp, const short* __restrict__ W,
    const float* __restrict__ bnscale, const float* __restrict__ bnshift,
    short* Hout, float* __restrict__ partials, int M) {
  constexpr int C = KD / 2;
  constexpr int NT = (ND > 128) ? 8 : ND / 16;
  constexpr int BR = (ND > 128) ? 64 : 128;
  constexpr int KT = KD / 32;
  __shared__ short lb[ND * 40];  // [ND][32+8] pad -> <=2-way bank alias on ds_read_b128
  __shared__ float lstats[2 * ND];
  const int tid = threadIdx.x;
  const int wave = tid >> 6, lane = tid & 63;
  const int rowOff = (ND > 128) ? (wave >> 1) * 32 : wave * 32;
  const int colOff = (ND > 128) ? (wave & 1) * 128 : 0;
  const int mBase = blockIdx.x * BR + rowOff;
  for (int i = tid; i < 2 * ND; i += 256) lstats[i] = 0.f;

  const short* aptr[2][2];
#pragma unroll
  for (int rg = 0; rg < 2; ++rg) {
    int m = mBase + rg * 16 + (lane & 15);
    if constexpr (GATHER) {
      int idx = KNNp[m];
      int bb = m / (S * 32);
      int s = (m - bb * (S * 32)) >> 5;
      aptr[rg][0] = A + ((size_t)bb * NPTS + idx) * C;
      aptr[rg][1] = FC + ((size_t)bb * S + s) * C;
    } else {
      aptr[rg][0] = A + (size_t)m * KD;
      aptr[rg][1] = A + (size_t)m * KD + C;
    }
  }
  const int koLane = (lane >> 4) * 8;
  f32x4 acc[2][NT];
#pragma unroll
  for (int rg = 0; rg < 2; ++rg)
#pragma unroll
    for (int nt = 0; nt < NT; ++nt) acc[rg][nt] = (f32x4){0.f, 0.f, 0.f, 0.f};

#pragma unroll
  for (int kt = 0; kt < KT; ++kt) {
    __syncthreads();
    constexpr int CH = (ND * 32) / 2048;
#pragma unroll
    for (int ch = 0; ch < CH; ++ch) {
      int e = ch * 2048 + tid * 8;
      int n = e >> 5, kk = e & 31;
      short8 v = *reinterpret_cast<const short8*>(W + (size_t)n * KD + kt * 32 + kk);
      *reinterpret_cast<short8*>(&lb[n * 40 + kk]) = v;
    }
    __syncthreads();
    const int half = (kt * 32 >= C) ? 1 : 0;
    const int ko = kt * 32 + koLane;
    const int koh = ko - half * C;
    short8 afrag[2];
#pragma unroll
    for (int rg = 0; rg < 2; ++rg) {
      short8 a = *reinterpret_cast<const short8*>(aptr[rg][half] + koh);
      if constexpr (BNA) {
        const float* scp = bnscale + ko;
        const float* shp = bnshift + ko;
#pragma unroll
        for (int j = 0; j < 8; ++j) {
          float v = bf2f(a[j]);
          v = fmaxf(v * scp[j] + shp[j], 0.f);
          a[j] = f2bf(v);
        }
      }
      afrag[rg] = a;
    }
#pragma unroll
    for (int nt = 0; nt < NT; ++nt) {
      short8 bfr = *reinterpret_cast<const short8*>(&lb[(colOff + nt * 16 + (lane & 15)) * 40 + koLane]);
      acc[0][nt] = mfma16(afrag[0], bfr, acc[0][nt]);
      acc[1][nt] = mfma16(afrag[1], bfr, acc[1][nt]);
    }
  }
  __syncthreads();  // all A-reads done before in-place stores (ND=256 waves share rows)

  // per-channel sum / sumsq partials
#pragma unroll
  for (int nt = 0; nt < NT; ++nt) {
    float s0 = 0.f, s1 = 0.f;
#pragma unroll
    for (int rg = 0; rg < 2; ++rg)
#pragma unroll
      for (int i = 0; i < 4; ++i) {
        float v = acc[rg][nt][i];
        s0 += v; s1 += v * v;
      }
    s0 += __shfl_xor(s0, 16); s0 += __shfl_xor(s0, 32);
    s1 += __shfl_xor(s1, 16); s1 += __shfl_xor(s1, 32);
    if (lane < 16) {
      atomicAdd(&lstats[colOff + nt * 16 + lane], s0);
      atomicAdd(&lstats[ND + colOff + nt * 16 + lane], s1);
    }
  }
  // store output (C/D layout: row = 4*(lane>>4)+i, col = lane&15)
#pragma unroll
  for (int rg = 0; rg < 2; ++rg)
#pragma unroll
    for (int nt = 0; nt < NT; ++nt)
#pragma unroll
      for (int i = 0; i < 4; ++i) {
        int m2 = mBase + rg * 16 + (lane >> 4) * 4 + i;
        int n = colOff + nt * 16 + (lane & 15);
        Hout[(size_t)m2 * ND + n] = f2bf(acc[rg][nt][i]);
      }
  __syncthreads();
  for (int i = tid; i < 2 * ND; i += 256)
    partials[(size_t)i * gridDim.x + blockIdx.x] = lstats[i];
}

// ---------- max over K with BN+ReLU -> f1 bf16 ----------
__global__ __launch_bounds__(128) void maxpool_f1_kernel(
    const short* __restrict__ h, const float* __restrict__ scale,
    const float* __restrict__ shift, short* __restrict__ f1) {
  const int bs = blockIdx.x, c = threadIdx.x;
  const float sc = scale[c], sh = shift[c];
  float m = 0.f;  // relu outputs >= 0
  for (int k = 0; k < 32; ++k) {
    float v = bf2f(h[((size_t)bs * 32 + k) * 128 + c]);
    m = fmaxf(m, fmaxf(v * sc + sh, 0.f));
  }
  f1[(size_t)bs * 128 + c] = f2bf(m);
}

// ---------- final: max over K with BN+ReLU, transposed fp32 out [B][C][S] ----------
__global__ __launch_bounds__(256) void maxpool_out_kernel(
    const short* __restrict__ h, const float* __restrict__ scale,
    const float* __restrict__ shift, float* __restrict__ out) {
  const int bs = blockIdx.x, c = threadIdx.x;
  const int b = bs >> 8, s = bs & 255;
  const float sc = scale[c], sh = shift[c];
  float m = 0.f;
  for (int k = 0; k < 32; ++k) {
    float v = bf2f(h[((size_t)bs * 32 + k) * 256 + c]);
    m = fmaxf(m, fmaxf(v * sc + sh, 0.f));
  }
  out[((size_t)b << 16) + ((size_t)c << 8) + s] = m;
}

// ---------- launch ----------
extern "C" void kernel_launch(void* const* d_in, const int* in_sizes, int n_in,
                              void* d_out, int out_size, void* d_ws, size_t ws_size,
                              hipStream_t stream) {
  (void)in_sizes; (void)n_in; (void)out_size; (void)ws_size;
  const float* x    = (const float*)d_in[0];
  const float* w1   = (const float*)d_in[1];
  const float* g1   = (const float*)d_in[2];
  const float* b1   = (const float*)d_in[3];
  const float* w2   = (const float*)d_in[4];
  const float* g2   = (const float*)d_in[5];
  const float* b2   = (const float*)d_in[6];
  const float* s1w1 = (const float*)d_in[7];
  const float* s1g1 = (const float*)d_in[8];
  const float* s1b1 = (const float*)d_in[9];
  const float* s1w2 = (const float*)d_in[10];
  const float* s1g2 = (const float*)d_in[11];
  const float* s1b2 = (const float*)d_in[12];
  const float* s2w1 = (const float*)d_in[13];
  const float* s2g1 = (const float*)d_in[14];
  const float* s2b1 = (const float*)d_in[15];
  const float* s2w2 = (const float*)d_in[16];
  const float* s2g2 = (const float*)d_in[17];
  const float* s2b2 = (const float*)d_in[18];
  float* out = (float*)d_out;

  char* ws = (char*)d_ws;
  size_t off = 0;
  auto alloc = [&](size_t bytes) -> char* {
    size_t p = (off + 255) & ~(size_t)255;
    off = p + bytes;
    return ws + p;
  };

  float* xyz      = (float*)alloc(32ull * 4096 * 3 * 4);
  short* h0       = (short*)alloc(32ull * 4096 * 64 * 2);
  short* hb       = (short*)alloc(32ull * 4096 * 64 * 2);
  short* fb       = (short*)alloc(32ull * 4096 * 64 * 2);
  int*   fps1     = (int*)alloc(32ull * 512 * 4);
  float* xyzc1    = (float*)alloc(32ull * 512 * 3 * 4);
  short* fcen1    = (short*)alloc(32ull * 512 * 64 * 2);
  int*   knn1     = (int*)alloc(32ull * 512 * 32 * 4);
  short* f1       = (short*)alloc(32ull * 512 * 128 * 2);
  int*   fps2     = (int*)alloc(32ull * 256 * 4);
  float* xyzc2    = (float*)alloc(32ull * 256 * 3 * 4);
  short* fcen2    = (short*)alloc(32ull * 256 * 128 * 2);
  int*   knn2     = (int*)alloc(32ull * 256 * 32 * 4);
  short* hbuf     = (short*)alloc(134217728ull);          // shared SG1/SG2 h buffer
  float* partials = (float*)alloc(2ull * 256 * 4096 * 4); // 8 MB
  float* totals   = (float*)alloc(512 * 4);
  float* scA  = (float*)alloc(64 * 4);  float* shA  = (float*)alloc(64 * 4);
  float* scBc = (float*)alloc(64 * 4);  float* shBc = (float*)alloc(64 * 4);
  float* sc1a = (float*)alloc(128 * 4); float* sh1a = (float*)alloc(128 * 4);
  float* sc1b = (float*)alloc(128 * 4); float* sh1b = (float*)alloc(128 * 4);
  float* sc2a = (float*)alloc(256 * 4); float* sh2a = (float*)alloc(256 * 4);
  float* sc2b = (float*)alloc(256 * 4); float* sh2b = (float*)alloc(256 * 4);
  short* w2b   = (short*)alloc(4096 * 2);
  short* s1w2b = (short*)alloc(16384 * 2);
  short* s2w2b = (short*)alloc(65536 * 2);
  short* W1pp  = (short*)alloc(16384 * 2);
  short* W2pp  = (short*)alloc(65536 * 2);

  prep_kernel<<<656, 256, 0, stream>>>(w2, s1w2, s2w2, s1w1, s2w1, w2b, s1w2b, s2w2b, W1pp, W2pp);
  stageA_kernel<<<512, 256, 0, stream>>>(x, w1, xyz, h0);
  stats64_kernel<<<256, 256, 0, stream>>>(h0, partials, 131072);
  reduce_kernel<<<128, 256, 0, stream>>>(partials, totals, 256);
  finalize_kernel<<<1, 64, 0, stream>>>(totals, g1, b1, scA, shA, 64, 1.f / 131072.f);
  gemm_kernel<64, 64, false, true, 1, 1><<<1024, 256, 0, stream>>>(
      h0, nullptr, nullptr, w2b, scA, shA, hb, partials, 131072);
  reduce_kernel<<<128, 256, 0, stream>>>(partials, totals, 1024);
  finalize_kernel<<<1, 64, 0, stream>>>(totals, g2, b2, scBc, shBc, 64, 1.f / 131072.f);
  apply_kernel<<<4096, 256, 0, stream>>>(hb, fb, scBc, shBc, 1048576, 63);

  fps_kernel<4096, 512><<<32, 256, 0, stream>>>(xyz, fps1);
  gather_kernel<512, 4096, 64><<<16384, 64, 0, stream>>>(fps1, xyz, fb, xyzc1, fcen1);
  knn_kernel<4096, 512><<<16384, 256, 0, stream>>>(xyz, xyzc1, knn1);

  gemm_kernel<128, 128, true, false, 4096, 512><<<4096, 256, 0, stream>>>(
      fb, fcen1, knn1, W1pp, nullptr, nullptr, hbuf, partials, 524288);
  reduce_kernel<<<256, 256, 0, stream>>>(partials, totals, 4096);
  finalize_kernel<<<1, 128, 0, stream>>>(totals, s1g1, s1b1, sc1a, sh1a, 128, 1.f / 524288.f);
  gemm_kernel<128, 128, false, true, 1, 1><<<4096, 256, 0, stream>>>(
      hbuf, nullptr, nullptr, s1w2b, sc1a, sh1a, hbuf, partials, 524288);
  reduce_kernel<<<256, 256, 0, stream>>>(partials, totals, 4096);
  finalize_kernel<<<1, 128, 0, stream>>>(totals, s1g2, s1b2, sc1b, sh1b, 128, 1.f / 524288.f);
  maxpool_f1_kernel<<<16384, 128, 0, stream>>>(hbuf, sc1b, sh1b, f1);

  fps_kernel<512, 256><<<32, 256, 0, stream>>>(xyzc1, fps2);
  gather_kernel<256, 512, 128><<<8192, 128, 0, stream>>>(fps2, xyzc1, f1, xyzc2, fcen2);
  knn_kernel<512, 256><<<8192, 256, 0, stream>>>(xyzc1, xyzc2, knn2);

  gemm_kernel<256, 256, true, false, 512, 256><<<4096, 256, 0, stream>>>(
      f1, fcen2, knn2, W2pp, nullptr, nullptr, hbuf, partials, 262144);
  reduce_kernel<<<512, 256, 0, stream>>>(partials, totals, 4096);
  finalize_kernel<<<1, 256, 0, stream>>>(totals, s2g1, s2b1, sc2a, sh2a, 256, 1.f / 262144.f);
  gemm_kernel<256, 256, false, true, 1, 1><<<4096, 256, 0, stream>>>(
      hbuf, nullptr, nullptr, s2w2b, sc2a, sh2a, hbuf, partials, 262144);
  reduce_kernel<<<512, 256, 0, stream>>>(partials, totals, 4096);
  finalize_kernel<<<1, 256, 0, stream>>>(totals, s2g2, s2b2, sc2b, sh2b, 256, 1.f / 262144.f);
  maxpool_out_kernel<<<8192, 256, 0, stream>>>(hbuf, sc2b, sh2b, out);
}

// Round 3
// 1766.604 us; speedup vs baseline: 1.1141x; 1.1141x over previous
//
#include <hip/hip_runtime.h>

// ---------- types & helpers ----------
typedef short short8 __attribute__((ext_vector_type(8)));
typedef _Float16 h8 __attribute__((ext_vector_type(8)));
typedef float f32x4 __attribute__((ext_vector_type(4)));

#define DEVI __device__ __forceinline__

DEVI float h2f(short s) { return (float)__builtin_bit_cast(_Float16, s); }
DEVI short f2h(float f) { return __builtin_bit_cast(short, (_Float16)f); }
DEVI f32x4 mfma16(short8 a, short8 b, f32x4 c) {
  return __builtin_amdgcn_mfma_f32_16x16x32_f16(
      __builtin_bit_cast(h8, a), __builtin_bit_cast(h8, b), c, 0, 0, 0);
}

// ---------- DPP 64-lane reductions (gfx9 pattern), result broadcast ----------
DEVI float wave_max_bcast(float v) {
  const int ID = 0xff800000;  // -inf
  int x = __builtin_bit_cast(int, v);
#define STEPM(ctrl)                                                     \
  {                                                                     \
    int t = __builtin_amdgcn_update_dpp(ID, x, ctrl, 0xf, 0xf, false);  \
    x = __builtin_bit_cast(int, fmaxf(__builtin_bit_cast(float, x),     \
                                      __builtin_bit_cast(float, t)));   \
  }
  STEPM(0x111) STEPM(0x112) STEPM(0x114) STEPM(0x118) STEPM(0x142) STEPM(0x143)
#undef STEPM
  return __builtin_bit_cast(float, __builtin_amdgcn_readlane(x, 63));
}
DEVI float wave_min_bcast_f(float v) {
  const int ID = 0x7f800000;  // +inf
  int x = __builtin_bit_cast(int, v);
#define STEPN(ctrl)                                                     \
  {                                                                     \
    int t = __builtin_amdgcn_update_dpp(ID, x, ctrl, 0xf, 0xf, false);  \
    x = __builtin_bit_cast(int, fminf(__builtin_bit_cast(float, x),     \
                                      __builtin_bit_cast(float, t)));   \
  }
  STEPN(0x111) STEPN(0x112) STEPN(0x114) STEPN(0x118) STEPN(0x142) STEPN(0x143)
#undef STEPN
  return __builtin_bit_cast(float, __builtin_amdgcn_readlane(x, 63));
}
DEVI unsigned wave_min_bcast_u(unsigned v) {
  const int ID = (int)0xffffffff;
  int x = (int)v;
#define STEPU(ctrl)                                                     \
  {                                                                     \
    int t = __builtin_amdgcn_update_dpp(ID, x, ctrl, 0xf, 0xf, false);  \
    x = (int)((unsigned)x < (unsigned)t ? (unsigned)x : (unsigned)t);   \
  }
  STEPU(0x111) STEPU(0x112) STEPU(0x114) STEPU(0x118) STEPU(0x142) STEPU(0x143)
#undef STEPU
  return (unsigned)__builtin_amdgcn_readlane(x, 63);
}

// ---------- weight prep: f16 casts + folded W'' = [w1a | w1b - w1a] ----------
__global__ __launch_bounds__(256) void prep_kernel(
    const float* __restrict__ w2, const float* __restrict__ s1w2,
    const float* __restrict__ s2w2, const float* __restrict__ s1w1,
    const float* __restrict__ s2w1, short* __restrict__ w2b,
    short* __restrict__ s1w2b, short* __restrict__ s2w2b,
    short* __restrict__ W1pp, short* __restrict__ W2pp) {
  int i = blockIdx.x * 256 + threadIdx.x;
  if (i < 4096) {
    w2b[i] = f2h(w2[i]);
  } else if (i < 20480) {
    int j = i - 4096; s1w2b[j] = f2h(s1w2[j]);
  } else if (i < 86016) {
    int j = i - 20480; s2w2b[j] = f2h(s2w2[j]);
  } else if (i < 102400) {
    int j = i - 86016; int c = j & 127;
    float v = s1w1[j]; if (c >= 64) v -= s1w1[j - 64];
    W1pp[j] = f2h(v);
  } else if (i < 167936) {
    int j = i - 102400; int c = j & 255;
    float v = s2w1[j]; if (c >= 128) v -= s2w1[j - 128];
    W2pp[j] = f2h(v);
  }
}

// ---------- stage A: xyz transpose + h0 = x @ w1^T (K=3, VALU fp32) ----------
__global__ __launch_bounds__(256) void stageA_kernel(
    const float* __restrict__ x, const float* __restrict__ w1,
    float* __restrict__ xyz, short* __restrict__ h0) {
  int i = blockIdx.x * 256 + threadIdx.x;  // b*4096 + n, < 131072
  int b = i >> 12, n = i & 4095;
  const float* xb = x + ((size_t)b * 3 << 12) + n;
  float x0 = xb[0], x1 = xb[4096], x2 = xb[8192];
  float* xp = xyz + (size_t)i * 3;
  xp[0] = x0; xp[1] = x1; xp[2] = x2;
  short* hp = h0 + ((size_t)i << 6);
#pragma unroll
  for (int o8 = 0; o8 < 8; ++o8) {
    short8 t;
#pragma unroll
    for (int j = 0; j < 8; ++j) {
      int o = o8 * 8 + j;
      float h = x0 * w1[o * 3] + x1 * w1[o * 3 + 1] + x2 * w1[o * 3 + 2];
      t[j] = f2h(h);
    }
    *reinterpret_cast<short8*>(hp + o8 * 8) = t;
  }
}

// ---------- channel stats for a [M][64] f16 tensor -> transposed partials ----------
__global__ __launch_bounds__(256) void stats64_kernel(
    const short* __restrict__ h, float* __restrict__ partials, int M) {
  __shared__ float l0[256], l1[256];
  const int tid = threadIdx.x;
  const int c = tid & 63, g = tid >> 6;
  float s0 = 0.f, s1 = 0.f;
  for (int m = blockIdx.x * 4 + g; m < M; m += gridDim.x * 4) {
    float v = h2f(h[(size_t)m * 64 + c]);
    s0 += v; s1 += v * v;
  }
  l0[tid] = s0; l1[tid] = s1;
  __syncthreads();
  if (g == 0) {
    for (int w = 1; w < 4; ++w) { s0 += l0[c + w * 64]; s1 += l1[c + w * 64]; }
    partials[(size_t)c * gridDim.x + blockIdx.x] = s0;
    partials[(size_t)(64 + c) * gridDim.x + blockIdx.x] = s1;
  }
}

// ---------- reduce partials[j][0..NB) -> totals[j] ----------
__global__ __launch_bounds__(256) void reduce_kernel(
    const float* __restrict__ partials, float* __restrict__ totals, int NB) {
  __shared__ float l[4];
  const int j = blockIdx.x, tid = threadIdx.x;
  float s = 0.f;
  for (int i = tid; i < NB; i += 256) s += partials[(size_t)j * NB + i];
#pragma unroll
  for (int off = 1; off < 64; off <<= 1) s += __shfl_xor(s, off);
  if ((tid & 63) == 0) l[tid >> 6] = s;
  __syncthreads();
  if (tid == 0) totals[j] = l[0] + l[1] + l[2] + l[3];
}

// ---------- finalize BN: scale = g*rsqrt(var+eps), shift = b - mean*scale ----------
__global__ void finalize_kernel(const float* __restrict__ totals,
                                const float* __restrict__ gamma,
                                const float* __restrict__ beta,
                                float* __restrict__ scale, float* __restrict__ shift,
                                int C, float invM) {
  int c = threadIdx.x;
  if (c < C) {
    float mean = totals[c] * invM;
    float var = totals[C + c] * invM - mean * mean;
    var = fmaxf(var, 0.f);
    float sc = gamma[c] / sqrtf(var + 1e-5f);
    scale[c] = sc;
    shift[c] = beta[c] - mean * sc;
  }
}

// ---------- elementwise BN+ReLU apply (f16 -> f16), 8 elems/thread ----------
__global__ __launch_bounds__(256) void apply_kernel(
    const short* __restrict__ h, short* __restrict__ f,
    const float* __restrict__ scale, const float* __restrict__ shift,
    int total8, int Cmask) {
  int t = blockIdx.x * 256 + threadIdx.x;
  if (t >= total8) return;
  size_t i = (size_t)t * 8;
  int c0 = (int)(i & (size_t)Cmask);
  short8 v = *reinterpret_cast<const short8*>(h + i);
  short8 o;
#pragma unroll
  for (int j = 0; j < 8; ++j) {
    float y = h2f(v[j]) * scale[c0 + j] + shift[c0 + j];
    o[j] = f2h(fmaxf(y, 0.f));
  }
  *reinterpret_cast<short8*>(f + i) = o;
}

// ---------- farthest point sampling; exact match to reference scan ----------
// 512 threads, DPP wave argmax + single barrier/iter (double-buffered LDS slots)
template <int NPTS, int NSEL>
__global__ __launch_bounds__(512) void fps_kernel(const float* __restrict__ xyz,
                                                  int* __restrict__ out) {
  constexpr int T = 512;
  constexpr int PT = NPTS / T;
  __shared__ float sx[NPTS], sy[NPTS], sz[NPTS];
  __shared__ float wv[2][8];
  __shared__ unsigned wi[2][8];
  const int tid = threadIdx.x, b = blockIdx.x;
  const int lane = tid & 63, wave = tid >> 6;
  const float* base = xyz + (size_t)b * NPTS * 3;
  float px[PT], py[PT], pz[PT], dmin[PT];
#pragma unroll
  for (int j = 0; j < PT; ++j) {
    int n = j * T + tid;
    px[j] = base[n * 3]; py[j] = base[n * 3 + 1]; pz[j] = base[n * 3 + 2];
    sx[n] = px[j]; sy[n] = py[j]; sz[n] = pz[j];
    dmin[j] = 1e10f;
  }
  __syncthreads();
  int far = 0;
  for (int it = 0; it < NSEL; ++it) {
    if (tid == 0) out[b * NSEL + it] = far;
    float cx = sx[far], cy = sy[far], cz = sz[far];
    float bv = -1.f; unsigned bi = 0x7fffffffu;
#pragma unroll
    for (int j = 0; j < PT; ++j) {
      float dx = __fsub_rn(px[j], cx), dy = __fsub_rn(py[j], cy), dz = __fsub_rn(pz[j], cz);
      float d = __fadd_rn(__fadd_rn(__fmul_rn(dx, dx), __fmul_rn(dy, dy)), __fmul_rn(dz, dz));
      float dm = fminf(dmin[j], d);
      dmin[j] = dm;
      if (dm > bv) { bv = dm; bi = (unsigned)(j * T + tid); }  // strict > keeps smallest n
    }
    float wmv = wave_max_bcast(bv);
    unsigned ci = (bv == wmv) ? bi : 0x7fffffffu;
    unsigned wmi = wave_min_bcast_u(ci);
    if (lane == 0) { wv[it & 1][wave] = wmv; wi[it & 1][wave] = wmi; }
    __syncthreads();
    float gv = wv[it & 1][0]; unsigned gi = wi[it & 1][0];
#pragma unroll
    for (int w = 1; w < 8; ++w) {
      float ov = wv[it & 1][w]; unsigned oi = wi[it & 1][w];
      if (ov > gv || (ov == gv && oi < gi)) { gv = ov; gi = oi; }
    }
    far = (int)gi;
  }
}

// ---------- kNN: 32 smallest (d, idx) per center; DPP argmin + incremental local min
template <int NPTS, int S>
__global__ __launch_bounds__(256) void knn_kernel(const float* __restrict__ pts,
                                                  const float* __restrict__ ctr,
                                                  int* __restrict__ knn) {
  constexpr int PT = NPTS / 256;
  __shared__ float wv[2][4];
  __shared__ unsigned wi[2][4];
  const int tid = threadIdx.x, bs = blockIdx.x;
  const int lane = tid & 63, wave = tid >> 6;
  const int b = bs / S;
  const float* base = pts + (size_t)b * NPTS * 3;
  const float qx = ctr[bs * 3], qy = ctr[bs * 3 + 1], qz = ctr[bs * 3 + 2];
  const float qq = __fadd_rn(__fadd_rn(__fmul_rn(qx, qx), __fmul_rn(qy, qy)), __fmul_rn(qz, qz));
  float d[PT];
#pragma unroll
  for (int j = 0; j < PT; ++j) {
    int n = j * 256 + tid;
    float x = base[n * 3], y = base[n * 3 + 1], z = base[n * 3 + 2];
    float pp = __fadd_rn(__fadd_rn(__fmul_rn(x, x), __fmul_rn(y, y)), __fmul_rn(z, z));
    float dot = __fadd_rn(__fadd_rn(__fmul_rn(qx, x), __fmul_rn(qy, y)), __fmul_rn(qz, z));
    d[j] = __fsub_rn(__fadd_rn(qq, pp), __fmul_rn(2.f, dot));
  }
  unsigned sel = 0;
  float bv = 3.4e38f; unsigned bi = 0x7fffffffu;
#pragma unroll
  for (int j = 0; j < PT; ++j)
    if (d[j] < bv) { bv = d[j]; bi = (unsigned)(j * 256 + tid); }
  for (int k = 0; k < 32; ++k) {
    float wmv = wave_min_bcast_f(bv);
    unsigned ci = (bv == wmv) ? bi : 0x7fffffffu;
    unsigned wmi = wave_min_bcast_u(ci);
    if (lane == 0) { wv[k & 1][wave] = wmv; wi[k & 1][wave] = wmi; }
    __syncthreads();
    float gv = wv[k & 1][0]; unsigned gi = wi[k & 1][0];
#pragma unroll
    for (int w = 1; w < 4; ++w) {
      float ov = wv[k & 1][w]; unsigned oi = wi[k & 1][w];
      if (ov < gv || (ov == gv && oi < gi)) { gv = ov; gi = oi; }
    }
    if (tid == 0) knn[(size_t)bs * 32 + k] = (int)gi;
    if ((gi & 255u) == (unsigned)tid) {  // only the winner rescans its candidates
      sel |= 1u << (gi >> 8);
      bv = 3.4e38f; bi = 0x7fffffffu;
#pragma unroll
      for (int j = 0; j < PT; ++j)
        if (!((sel >> j) & 1u) && d[j] < bv) { bv = d[j]; bi = (unsigned)(j * 256 + tid); }
    }
  }
}

// ---------- gather centers: xyz + features at fps indices ----------
template <int S, int NPTS, int C>
__global__ void gather_kernel(const int* __restrict__ fps, const float* __restrict__ xyzsrc,
                              const short* __restrict__ fsrc, float* __restrict__ xyzdst,
                              short* __restrict__ fdst) {
  const int bs = blockIdx.x, tid = threadIdx.x;
  const int b = bs / S;
  const int idx = fps[bs];
  fdst[(size_t)bs * C + tid] = fsrc[((size_t)b * NPTS + idx) * C + tid];
  if (tid < 3) xyzdst[(size_t)bs * 3 + tid] = xyzsrc[((size_t)b * NPTS + idx) * 3 + tid];
}

// ---------- MFMA GEMM: [M][KD] @ [ND][KD]^T -> [M][ND] f16 + BN partials
// GATHER: A-row m=(b,s,k): first KD/2 from F[b, knn[m], :], second from FC[b, s, :]
// BNA: apply scale/shift + ReLU to A elements on load (f16 in/out)
template <int KD, int ND, bool GATHER, bool BNA, int NPTS, int S>
__global__ __launch_bounds__(256) void gemm_kernel(
    const short* A, const short* FC, const int* KNNp, const short* __restrict__ W,
    const float* __restrict__ bnscale, const float* __restrict__ bnshift,
    short* Hout, float* __restrict__ partials, int M) {
  constexpr int C = KD / 2;
  constexpr int NT = (ND > 128) ? 8 : ND / 16;
  constexpr int BR = (ND > 128) ? 64 : 128;
  constexpr int KT = KD / 32;
  __shared__ short lb[ND * 40];  // [ND][32+8] pad -> <=2-way bank alias on ds_read_b128
  __shared__ float lstats[2 * ND];
  const int tid = threadIdx.x;
  const int wave = tid >> 6, lane = tid & 63;
  const int rowOff = (ND > 128) ? (wave >> 1) * 32 : wave * 32;
  const int colOff = (ND > 128) ? (wave & 1) * 128 : 0;
  const int mBase = blockIdx.x * BR + rowOff;
  for (int i = tid; i < 2 * ND; i += 256) lstats[i] = 0.f;

  const short* aptr[2][2];
#pragma unroll
  for (int rg = 0; rg < 2; ++rg) {
    int m = mBase + rg * 16 + (lane & 15);
    if constexpr (GATHER) {
      int idx = KNNp[m];
      int bb = m / (S * 32);
      int s = (m - bb * (S * 32)) >> 5;
      aptr[rg][0] = A + ((size_t)bb * NPTS + idx) * C;
      aptr[rg][1] = FC + ((size_t)bb * S + s) * C;
    } else {
      aptr[rg][0] = A + (size_t)m * KD;
      aptr[rg][1] = A + (size_t)m * KD + C;
    }
  }
  const int koLane = (lane >> 4) * 8;
  f32x4 acc[2][NT];
#pragma unroll
  for (int rg = 0; rg < 2; ++rg)
#pragma unroll
    for (int nt = 0; nt < NT; ++nt) acc[rg][nt] = (f32x4){0.f, 0.f, 0.f, 0.f};

#pragma unroll
  for (int kt = 0; kt < KT; ++kt) {
    __syncthreads();
    constexpr int CH = (ND * 32) / 2048;
#pragma unroll
    for (int ch = 0; ch < CH; ++ch) {
      int e = ch * 2048 + tid * 8;
      int n = e >> 5, kk = e & 31;
      short8 v = *reinterpret_cast<const short8*>(W + (size_t)n * KD + kt * 32 + kk);
      *reinterpret_cast<short8*>(&lb[n * 40 + kk]) = v;
    }
    __syncthreads();
    const int half = (kt * 32 >= C) ? 1 : 0;
    const int ko = kt * 32 + koLane;
    const int koh = ko - half * C;
    short8 afrag[2];
#pragma unroll
    for (int rg = 0; rg < 2; ++rg) {
      short8 a = *reinterpret_cast<const short8*>(aptr[rg][half] + koh);
      if constexpr (BNA) {
        const float* scp = bnscale + ko;
        const float* shp = bnshift + ko;
#pragma unroll
        for (int j = 0; j < 8; ++j) {
          float v = h2f(a[j]);
          v = fmaxf(v * scp[j] + shp[j], 0.f);
          a[j] = f2h(v);
        }
      }
      afrag[rg] = a;
    }
#pragma unroll
    for (int nt = 0; nt < NT; ++nt) {
      short8 bfr = *reinterpret_cast<const short8*>(&lb[(colOff + nt * 16 + (lane & 15)) * 40 + koLane]);
      acc[0][nt] = mfma16(afrag[0], bfr, acc[0][nt]);
      acc[1][nt] = mfma16(afrag[1], bfr, acc[1][nt]);
    }
  }
  __syncthreads();  // all A-reads done before in-place stores (ND=256 waves share rows)

  // per-channel sum / sumsq partials
#pragma unroll
  for (int nt = 0; nt < NT; ++nt) {
    float s0 = 0.f, s1 = 0.f;
#pragma unroll
    for (int rg = 0; rg < 2; ++rg)
#pragma unroll
      for (int i = 0; i < 4; ++i) {
        float v = acc[rg][nt][i];
        s0 += v; s1 += v * v;
      }
    s0 += __shfl_xor(s0, 16); s0 += __shfl_xor(s0, 32);
    s1 += __shfl_xor(s1, 16); s1 += __shfl_xor(s1, 32);
    if (lane < 16) {
      atomicAdd(&lstats[colOff + nt * 16 + lane], s0);
      atomicAdd(&lstats[ND + colOff + nt * 16 + lane], s1);
    }
  }
  // store output (C/D layout: row = 4*(lane>>4)+i, col = lane&15)
#pragma unroll
  for (int rg = 0; rg < 2; ++rg)
#pragma unroll
    for (int nt = 0; nt < NT; ++nt)
#pragma unroll
      for (int i = 0; i < 4; ++i) {
        int m2 = mBase + rg * 16 + (lane >> 4) * 4 + i;
        int n = colOff + nt * 16 + (lane & 15);
        Hout[(size_t)m2 * ND + n] = f2h(acc[rg][nt][i]);
      }
  __syncthreads();
  for (int i = tid; i < 2 * ND; i += 256)
    partials[(size_t)i * gridDim.x + blockIdx.x] = lstats[i];
}

// ---------- max over K with BN+ReLU -> f1 f16 ----------
__global__ __launch_bounds__(128) void maxpool_f1_kernel(
    const short* __restrict__ h, const float* __restrict__ scale,
    const float* __restrict__ shift, short* __restrict__ f1) {
  const int bs = blockIdx.x, c = threadIdx.x;
  const float sc = scale[c], sh = shift[c];
  float m = 0.f;  // relu outputs >= 0
  for (int k = 0; k < 32; ++k) {
    float v = h2f(h[((size_t)bs * 32 + k) * 128 + c]);
    m = fmaxf(m, fmaxf(v * sc + sh, 0.f));
  }
  f1[(size_t)bs * 128 + c] = f2h(m);
}

// ---------- final: max over K with BN+ReLU, transposed fp32 out [B][C][S] ----------
__global__ __launch_bounds__(256) void maxpool_out_kernel(
    const short* __restrict__ h, const float* __restrict__ scale,
    const float* __restrict__ shift, float* __restrict__ out) {
  const int bs = blockIdx.x, c = threadIdx.x;
  const int b = bs >> 8, s = bs & 255;
  const float sc = scale[c], sh = shift[c];
  float m = 0.f;
  for (int k = 0; k < 32; ++k) {
    float v = h2f(h[((size_t)bs * 32 + k) * 256 + c]);
    m = fmaxf(m, fmaxf(v * sc + sh, 0.f));
  }
  out[((size_t)b << 16) + ((size_t)c << 8) + s] = m;
}

// ---------- launch ----------
extern "C" void kernel_launch(void* const* d_in, const int* in_sizes, int n_in,
                              void* d_out, int out_size, void* d_ws, size_t ws_size,
                              hipStream_t stream) {
  (void)in_sizes; (void)n_in; (void)out_size; (void)ws_size;
  const float* x    = (const float*)d_in[0];
  const float* w1   = (const float*)d_in[1];
  const float* g1   = (const float*)d_in[2];
  const float* b1   = (const float*)d_in[3];
  const float* w2   = (const float*)d_in[4];
  const float* g2   = (const float*)d_in[5];
  const float* b2   = (const float*)d_in[6];
  const float* s1w1 = (const float*)d_in[7];
  const float* s1g1 = (const float*)d_in[8];
  const float* s1b1 = (const float*)d_in[9];
  const float* s1w2 = (const float*)d_in[10];
  const float* s1g2 = (const float*)d_in[11];
  const float* s1b2 = (const float*)d_in[12];
  const float* s2w1 = (const float*)d_in[13];
  const float* s2g1 = (const float*)d_in[14];
  const float* s2b1 = (const float*)d_in[15];
  const float* s2w2 = (const float*)d_in[16];
  const float* s2g2 = (const float*)d_in[17];
  const float* s2b2 = (const float*)d_in[18];
  float* out = (float*)d_out;

  char* ws = (char*)d_ws;
  size_t off = 0;
  auto alloc = [&](size_t bytes) -> char* {
    size_t p = (off + 255) & ~(size_t)255;
    off = p + bytes;
    return ws + p;
  };

  float* xyz      = (float*)alloc(32ull * 4096 * 3 * 4);
  short* h0       = (short*)alloc(32ull * 4096 * 64 * 2);
  short* hb       = (short*)alloc(32ull * 4096 * 64 * 2);
  short* fb       = (short*)alloc(32ull * 4096 * 64 * 2);
  int*   fps1     = (int*)alloc(32ull * 512 * 4);
  float* xyzc1    = (float*)alloc(32ull * 512 * 3 * 4);
  short* fcen1    = (short*)alloc(32ull * 512 * 64 * 2);
  int*   knn1     = (int*)alloc(32ull * 512 * 32 * 4);
  short* f1       = (short*)alloc(32ull * 512 * 128 * 2);
  int*   fps2     = (int*)alloc(32ull * 256 * 4);
  float* xyzc2    = (float*)alloc(32ull * 256 * 3 * 4);
  short* fcen2    = (short*)alloc(32ull * 256 * 128 * 2);
  int*   knn2     = (int*)alloc(32ull * 256 * 32 * 4);
  short* hbuf     = (short*)alloc(134217728ull);          // shared SG1/SG2 h buffer
  float* partials = (float*)alloc(2ull * 256 * 4096 * 4); // 8 MB
  float* totals   = (float*)alloc(512 * 4);
  float* scA  = (float*)alloc(64 * 4);  float* shA  = (float*)alloc(64 * 4);
  float* scBc = (float*)alloc(64 * 4);  float* shBc = (float*)alloc(64 * 4);
  float* sc1a = (float*)alloc(128 * 4); float* sh1a = (float*)alloc(128 * 4);
  float* sc1b = (float*)alloc(128 * 4); float* sh1b = (float*)alloc(128 * 4);
  float* sc2a = (float*)alloc(256 * 4); float* sh2a = (float*)alloc(256 * 4);
  float* sc2b = (float*)alloc(256 * 4); float* sh2b = (float*)alloc(256 * 4);
  short* w2b   = (short*)alloc(4096 * 2);
  short* s1w2b = (short*)alloc(16384 * 2);
  short* s2w2b = (short*)alloc(65536 * 2);
  short* W1pp  = (short*)alloc(16384 * 2);
  short* W2pp  = (short*)alloc(65536 * 2);

  prep_kernel<<<656, 256, 0, stream>>>(w2, s1w2, s2w2, s1w1, s2w1, w2b, s1w2b, s2w2b, W1pp, W2pp);
  stageA_kernel<<<512, 256, 0, stream>>>(x, w1, xyz, h0);
  stats64_kernel<<<256, 256, 0, stream>>>(h0, partials, 131072);
  reduce_kernel<<<128, 256, 0, stream>>>(partials, totals, 256);
  finalize_kernel<<<1, 64, 0, stream>>>(totals, g1, b1, scA, shA, 64, 1.f / 131072.f);
  gemm_kernel<64, 64, false, true, 1, 1><<<1024, 256, 0, stream>>>(
      h0, nullptr, nullptr, w2b, scA, shA, hb, partials, 131072);
  reduce_kernel<<<128, 256, 0, stream>>>(partials, totals, 1024);
  finalize_kernel<<<1, 64, 0, stream>>>(totals, g2, b2, scBc, shBc, 64, 1.f / 131072.f);
  apply_kernel<<<4096, 256, 0, stream>>>(hb, fb, scBc, shBc, 1048576, 63);

  fps_kernel<4096, 512><<<32, 512, 0, stream>>>(xyz, fps1);
  gather_kernel<512, 4096, 64><<<16384, 64, 0, stream>>>(fps1, xyz, fb, xyzc1, fcen1);
  knn_kernel<4096, 512><<<16384, 256, 0, stream>>>(xyz, xyzc1, knn1);

  gemm_kernel<128, 128, true, false, 4096, 512><<<4096, 256, 0, stream>>>(
      fb, fcen1, knn1, W1pp, nullptr, nullptr, hbuf, partials, 524288);
  reduce_kernel<<<256, 256, 0, stream>>>(partials, totals, 4096);
  finalize_kernel<<<1, 128, 0, stream>>>(totals, s1g1, s1b1, sc1a, sh1a, 128, 1.f / 524288.f);
  gemm_kernel<128, 128, false, true, 1, 1><<<4096, 256, 0, stream>>>(
      hbuf, nullptr, nullptr, s1w2b, sc1a, sh1a, hbuf, partials, 524288);
  reduce_kernel<<<256, 256, 0, stream>>>(partials, totals, 4096);
  finalize_kernel<<<1, 128, 0, stream>>>(totals, s1g2, s1b2, sc1b, sh1b, 128, 1.f / 524288.f);
  maxpool_f1_kernel<<<16384, 128, 0, stream>>>(hbuf, sc1b, sh1b, f1);

  fps_kernel<512, 256><<<32, 512, 0, stream>>>(xyzc1, fps2);
  gather_kernel<256, 512, 128><<<8192, 128, 0, stream>>>(fps2, xyzc1, f1, xyzc2, fcen2);
  knn_kernel<512, 256><<<8192, 256, 0, stream>>>(xyzc1, xyzc2, knn2);

  gemm_kernel<256, 256, true, false, 512, 256><<<4096, 256, 0, stream>>>(
      f1, fcen2, knn2, W2pp, nullptr, nullptr, hbuf, partials, 262144);
  reduce_kernel<<<512, 256, 0, stream>>>(partials, totals, 4096);
  finalize_kernel<<<1, 256, 0, stream>>>(totals, s2g1, s2b1, sc2a, sh2a, 256, 1.f / 262144.f);
  gemm_kernel<256, 256, false, true, 1, 1><<<4096, 256, 0, stream>>>(
      hbuf, nullptr, nullptr, s2w2b, sc2a, sh2a, hbuf, partials, 262144);
  reduce_kernel<<<512, 256, 0, stream>>>(partials, totals, 4096);
  finalize_kernel<<<1, 256, 0, stream>>>(totals, s2g2, s2b2, sc2b, sh2b, 256, 1.f / 262144.f);
  maxpool_out_kernel<<<8192, 256, 0, stream>>>(hbuf, sc2b, sh2b, out);
}

// Round 4
// 1710.731 us; speedup vs baseline: 1.1505x; 1.0327x over previous
//
#include <hip/hip_runtime.h>

// ---------- types & helpers ----------
typedef short short8 __attribute__((ext_vector_type(8)));
typedef _Float16 h8 __attribute__((ext_vector_type(8)));
typedef float f32x4 __attribute__((ext_vector_type(4)));

#define DEVI __device__ __forceinline__

DEVI float h2f(short s) { return (float)__builtin_bit_cast(_Float16, s); }
DEVI short f2h(float f) { return __builtin_bit_cast(short, (_Float16)f); }
DEVI f32x4 mfma16(short8 a, short8 b, f32x4 c) {
  return __builtin_amdgcn_mfma_f32_16x16x32_f16(
      __builtin_bit_cast(h8, a), __builtin_bit_cast(h8, b), c, 0, 0, 0);
}

// ---------- DPP 64-lane reductions (gfx9 pattern), result broadcast ----------
DEVI float wave_max_bcast(float v) {
  const int ID = 0xff800000;  // -inf
  int x = __builtin_bit_cast(int, v);
#define STEPM(ctrl)                                                     \
  {                                                                     \
    int t = __builtin_amdgcn_update_dpp(ID, x, ctrl, 0xf, 0xf, false);  \
    x = __builtin_bit_cast(int, fmaxf(__builtin_bit_cast(float, x),     \
                                      __builtin_bit_cast(float, t)));   \
  }
  STEPM(0x111) STEPM(0x112) STEPM(0x114) STEPM(0x118) STEPM(0x142) STEPM(0x143)
#undef STEPM
  return __builtin_bit_cast(float, __builtin_amdgcn_readlane(x, 63));
}
DEVI float wave_min_bcast_f(float v) {
  const int ID = 0x7f800000;  // +inf
  int x = __builtin_bit_cast(int, v);
#define STEPN(ctrl)                                                     \
  {                                                                     \
    int t = __builtin_amdgcn_update_dpp(ID, x, ctrl, 0xf, 0xf, false);  \
    x = __builtin_bit_cast(int, fminf(__builtin_bit_cast(float, x),     \
                                      __builtin_bit_cast(float, t)));   \
  }
  STEPN(0x111) STEPN(0x112) STEPN(0x114) STEPN(0x118) STEPN(0x142) STEPN(0x143)
#undef STEPN
  return __builtin_bit_cast(float, __builtin_amdgcn_readlane(x, 63));
}
DEVI unsigned wave_min_bcast_u(unsigned v) {
  const int ID = (int)0xffffffff;
  int x = (int)v;
#define STEPU(ctrl)                                                     \
  {                                                                     \
    int t = __builtin_amdgcn_update_dpp(ID, x, ctrl, 0xf, 0xf, false);  \
    x = (int)((unsigned)x < (unsigned)t ? (unsigned)x : (unsigned)t);   \
  }
  STEPU(0x111) STEPU(0x112) STEPU(0x114) STEPU(0x118) STEPU(0x142) STEPU(0x143)
#undef STEPU
  return (unsigned)__builtin_amdgcn_readlane(x, 63);
}

// ---------- weight prep: f16 casts + folded W'' = [w1a | w1b - w1a] ----------
__global__ __launch_bounds__(256) void prep_kernel(
    const float* __restrict__ w2, const float* __restrict__ s1w2,
    const float* __restrict__ s2w2, const float* __restrict__ s1w1,
    const float* __restrict__ s2w1, short* __restrict__ w2b,
    short* __restrict__ s1w2b, short* __restrict__ s2w2b,
    short* __restrict__ W1pp, short* __restrict__ W2pp) {
  int i = blockIdx.x * 256 + threadIdx.x;
  if (i < 4096) {
    w2b[i] = f2h(w2[i]);
  } else if (i < 20480) {
    int j = i - 4096; s1w2b[j] = f2h(s1w2[j]);
  } else if (i < 86016) {
    int j = i - 20480; s2w2b[j] = f2h(s2w2[j]);
  } else if (i < 102400) {
    int j = i - 86016; int c = j & 127;
    float v = s1w1[j]; if (c >= 64) v -= s1w1[j - 64];
    W1pp[j] = f2h(v);
  } else if (i < 167936) {
    int j = i - 102400; int c = j & 255;
    float v = s2w1[j]; if (c >= 128) v -= s2w1[j - 128];
    W2pp[j] = f2h(v);
  }
}

// ---------- stage A: xyz transpose + h0 = x @ w1^T (K=3, VALU fp32) ----------
__global__ __launch_bounds__(256) void stageA_kernel(
    const float* __restrict__ x, const float* __restrict__ w1,
    float* __restrict__ xyz, short* __restrict__ h0) {
  int i = blockIdx.x * 256 + threadIdx.x;  // b*4096 + n, < 131072
  int b = i >> 12, n = i & 4095;
  const float* xb = x + ((size_t)b * 3 << 12) + n;
  float x0 = xb[0], x1 = xb[4096], x2 = xb[8192];
  float* xp = xyz + (size_t)i * 3;
  xp[0] = x0; xp[1] = x1; xp[2] = x2;
  short* hp = h0 + ((size_t)i << 6);
#pragma unroll
  for (int o8 = 0; o8 < 8; ++o8) {
    short8 t;
#pragma unroll
    for (int j = 0; j < 8; ++j) {
      int o = o8 * 8 + j;
      float h = x0 * w1[o * 3] + x1 * w1[o * 3 + 1] + x2 * w1[o * 3 + 2];
      t[j] = f2h(h);
    }
    *reinterpret_cast<short8*>(hp + o8 * 8) = t;
  }
}

// ---------- channel stats for a [M][64] f16 tensor -> transposed partials ----------
__global__ __launch_bounds__(256) void stats64_kernel(
    const short* __restrict__ h, float* __restrict__ partials, int M) {
  __shared__ float l0[256], l1[256];
  const int tid = threadIdx.x;
  const int c = tid & 63, g = tid >> 6;
  float s0 = 0.f, s1 = 0.f;
  for (int m = blockIdx.x * 4 + g; m < M; m += gridDim.x * 4) {
    float v = h2f(h[(size_t)m * 64 + c]);
    s0 += v; s1 += v * v;
  }
  l0[tid] = s0; l1[tid] = s1;
  __syncthreads();
  if (g == 0) {
    for (int w = 1; w < 4; ++w) { s0 += l0[c + w * 64]; s1 += l1[c + w * 64]; }
    partials[(size_t)c * gridDim.x + blockIdx.x] = s0;
    partials[(size_t)(64 + c) * gridDim.x + blockIdx.x] = s1;
  }
}

// ---------- reduce partials[j][0..NB) -> totals[j] ----------
__global__ __launch_bounds__(256) void reduce_kernel(
    const float* __restrict__ partials, float* __restrict__ totals, int NB) {
  __shared__ float l[4];
  const int j = blockIdx.x, tid = threadIdx.x;
  float s = 0.f;
  for (int i = tid; i < NB; i += 256) s += partials[(size_t)j * NB + i];
#pragma unroll
  for (int off = 1; off < 64; off <<= 1) s += __shfl_xor(s, off);
  if ((tid & 63) == 0) l[tid >> 6] = s;
  __syncthreads();
  if (tid == 0) totals[j] = l[0] + l[1] + l[2] + l[3];
}

// ---------- finalize BN: scale = g*rsqrt(var+eps), shift = b - mean*scale ----------
__global__ void finalize_kernel(const float* __restrict__ totals,
                                const float* __restrict__ gamma,
                                const float* __restrict__ beta,
                                float* __restrict__ scale, float* __restrict__ shift,
                                int C, float invM) {
  int c = threadIdx.x;
  if (c < C) {
    float mean = totals[c] * invM;
    float var = totals[C + c] * invM - mean * mean;
    var = fmaxf(var, 0.f);
    float sc = gamma[c] / sqrtf(var + 1e-5f);
    scale[c] = sc;
    shift[c] = beta[c] - mean * sc;
  }
}

// ---------- elementwise BN+ReLU apply (f16 -> f16), 8 elems/thread ----------
__global__ __launch_bounds__(256) void apply_kernel(
    const short* __restrict__ h, short* __restrict__ f,
    const float* __restrict__ scale, const float* __restrict__ shift,
    int total8, int Cmask) {
  int t = blockIdx.x * 256 + threadIdx.x;
  if (t >= total8) return;
  size_t i = (size_t)t * 8;
  int c0 = (int)(i & (size_t)Cmask);
  short8 v = *reinterpret_cast<const short8*>(h + i);
  short8 o;
#pragma unroll
  for (int j = 0; j < 8; ++j) {
    float y = h2f(v[j]) * scale[c0 + j] + shift[c0 + j];
    o[j] = f2h(fmaxf(y, 0.f));
  }
  *reinterpret_cast<short8*>(f + i) = o;
}

// ---------- farthest point sampling v3 ----------
// Value-only fmin/fmax update loop (10 VALU/pt), winner rescan for index,
// per-wave winner writes (v,x,y,z,idx) to LDS -> lane-parallel DPP row_ror
// cross-wave argmax carrying coords (no dependent coord lookup after combine).
// One barrier per iteration (double-buffered slots). Exact numpy tie-break.
template <int NPTS, int T>
__global__ __launch_bounds__(T) void fps_kernel(const float* __restrict__ xyz,
                                                int* __restrict__ out, int nsel) {
  constexpr int PT = NPTS / T;
  constexpr int NW = T / 64;
  __shared__ float4 wslot[2][NW];
  __shared__ unsigned widx[2][NW];
  __shared__ float c0[3];
  const int tid = threadIdx.x, b = blockIdx.x;
  const int lane = tid & 63, wave = tid >> 6;
  const float* base = xyz + (size_t)b * NPTS * 3;
  float px[PT], py[PT], pz[PT], dmin[PT];
#pragma unroll
  for (int j = 0; j < PT; ++j) {
    int n = j * T + tid;
    px[j] = base[n * 3]; py[j] = base[n * 3 + 1]; pz[j] = base[n * 3 + 2];
    dmin[j] = 1e10f;
  }
  if (tid == 0) { c0[0] = px[0]; c0[1] = py[0]; c0[2] = pz[0]; }
  __syncthreads();
  int far = 0;
  float cx = c0[0], cy = c0[1], cz = c0[2];
  for (int it = 0; it < nsel; ++it) {
    if (tid == 0) out[b * nsel + it] = far;
    float bv = -1.f;
#pragma unroll
    for (int j = 0; j < PT; ++j) {
      float dx = __fsub_rn(px[j], cx), dy = __fsub_rn(py[j], cy), dz = __fsub_rn(pz[j], cz);
      float d = __fadd_rn(__fadd_rn(__fmul_rn(dx, dx), __fmul_rn(dy, dy)), __fmul_rn(dz, dz));
      float dm = fminf(dmin[j], d);
      dmin[j] = dm;
      bv = fmaxf(bv, dm);
    }
    float wmv = wave_max_bcast(bv);
    // rescan (descending j so the LAST write = smallest index)
    unsigned ci = 0xffffffffu; float sxr = 0.f, syr = 0.f, szr = 0.f;
#pragma unroll
    for (int j = PT - 1; j >= 0; --j)
      if (dmin[j] == wmv) { ci = (unsigned)(j * T + tid); sxr = px[j]; syr = py[j]; szr = pz[j]; }
    unsigned wmi = wave_min_bcast_u(ci);
    const int bsel = it & 1;
    if (ci == wmi) {  // exactly one lane per wave
      wslot[bsel][wave] = make_float4(wmv, sxr, syr, szr);
      widx[bsel][wave] = wmi;
    }
    __syncthreads();
    // lane-parallel cross-wave combine: lane reads slot (lane & (NW-1)),
    // then log2(NW) DPP row_ror steps carrying (v, idx, x, y, z).
    const int e = lane & (NW - 1);
    float4 s = wslot[bsel][e];
    unsigned si = widx[bsel][e];
    float v = s.x, xx = s.y, yy = s.z, zz = s.w;
#define CMB(ctrl)                                                                        \
  {                                                                                      \
    float v2 = __builtin_bit_cast(                                                       \
        float, __builtin_amdgcn_update_dpp(0, __builtin_bit_cast(int, v), ctrl, 0xf, 0xf, true)); \
    unsigned i2 = (unsigned)__builtin_amdgcn_update_dpp(0, (int)si, ctrl, 0xf, 0xf, true);\
    float x2 = __builtin_bit_cast(                                                       \
        float, __builtin_amdgcn_update_dpp(0, __builtin_bit_cast(int, xx), ctrl, 0xf, 0xf, true)); \
    float y2 = __builtin_bit_cast(                                                       \
        float, __builtin_amdgcn_update_dpp(0, __builtin_bit_cast(int, yy), ctrl, 0xf, 0xf, true)); \
    float z2 = __builtin_bit_cast(                                                       \
        float, __builtin_amdgcn_update_dpp(0, __builtin_bit_cast(int, zz), ctrl, 0xf, 0xf, true)); \
    bool bt = (v2 > v) || (v2 == v && i2 < si);                                          \
    v = bt ? v2 : v; si = bt ? i2 : si; xx = bt ? x2 : xx; yy = bt ? y2 : yy; zz = bt ? z2 : zz; \
  }
    if constexpr (NW >= 2) CMB(0x121)   // row_ror:1
    if constexpr (NW >= 4) CMB(0x122)   // row_ror:2
    if constexpr (NW >= 8) CMB(0x124)   // row_ror:4
    if constexpr (NW >= 16) CMB(0x128)  // row_ror:8
#undef CMB
    far = (int)si; cx = xx; cy = yy; cz = zz;
  }
}

// ---------- kNN: 32 smallest (d, idx) per center; DPP argmin + incremental local min
template <int NPTS, int S>
__global__ __launch_bounds__(256) void knn_kernel(const float* __restrict__ pts,
                                                  const float* __restrict__ ctr,
                                                  int* __restrict__ knn) {
  constexpr int PT = NPTS / 256;
  __shared__ float wv[2][4];
  __shared__ unsigned wi[2][4];
  const int tid = threadIdx.x, bs = blockIdx.x;
  const int lane = tid & 63, wave = tid >> 6;
  const int b = bs / S;
  const float* base = pts + (size_t)b * NPTS * 3;
  const float qx = ctr[bs * 3], qy = ctr[bs * 3 + 1], qz = ctr[bs * 3 + 2];
  const float qq = __fadd_rn(__fadd_rn(__fmul_rn(qx, qx), __fmul_rn(qy, qy)), __fmul_rn(qz, qz));
  float d[PT];
#pragma unroll
  for (int j = 0; j < PT; ++j) {
    int n = j * 256 + tid;
    float x = base[n * 3], y = base[n * 3 + 1], z = base[n * 3 + 2];
    float pp = __fadd_rn(__fadd_rn(__fmul_rn(x, x), __fmul_rn(y, y)), __fmul_rn(z, z));
    float dot = __fadd_rn(__fadd_rn(__fmul_rn(qx, x), __fmul_rn(qy, y)), __fmul_rn(qz, z));
    d[j] = __fsub_rn(__fadd_rn(qq, pp), __fmul_rn(2.f, dot));
  }
  unsigned sel = 0;
  float bv = 3.4e38f; unsigned bi = 0x7fffffffu;
#pragma unroll
  for (int j = 0; j < PT; ++j)
    if (d[j] < bv) { bv = d[j]; bi = (unsigned)(j * 256 + tid); }
  for (int k = 0; k < 32; ++k) {
    float wmv = wave_min_bcast_f(bv);
    unsigned ci = (bv == wmv) ? bi : 0x7fffffffu;
    unsigned wmi = wave_min_bcast_u(ci);
    if (lane == 0) { wv[k & 1][wave] = wmv; wi[k & 1][wave] = wmi; }
    __syncthreads();
    float gv = wv[k & 1][0]; unsigned gi = wi[k & 1][0];
#pragma unroll
    for (int w = 1; w < 4; ++w) {
      float ov = wv[k & 1][w]; unsigned oi = wi[k & 1][w];
      if (ov < gv || (ov == gv && oi < gi)) { gv = ov; gi = oi; }
    }
    if (tid == 0) knn[(size_t)bs * 32 + k] = (int)gi;
    if ((gi & 255u) == (unsigned)tid) {  // only the winner rescans its candidates
      sel |= 1u << (gi >> 8);
      bv = 3.4e38f; bi = 0x7fffffffu;
#pragma unroll
      for (int j = 0; j < PT; ++j)
        if (!((sel >> j) & 1u) && d[j] < bv) { bv = d[j]; bi = (unsigned)(j * 256 + tid); }
    }
  }
}

// ---------- gather centers: xyz + features at fps indices ----------
template <int S, int NPTS, int C>
__global__ void gather_kernel(const int* __restrict__ fps, const float* __restrict__ xyzsrc,
                              const short* __restrict__ fsrc, float* __restrict__ xyzdst,
                              short* __restrict__ fdst) {
  const int bs = blockIdx.x, tid = threadIdx.x;
  const int b = bs / S;
  const int idx = fps[bs];
  fdst[(size_t)bs * C + tid] = fsrc[((size_t)b * NPTS + idx) * C + tid];
  if (tid < 3) xyzdst[(size_t)bs * 3 + tid] = xyzsrc[((size_t)b * NPTS + idx) * 3 + tid];
}

// ---------- MFMA GEMM: [M][KD] @ [ND][KD]^T -> [M][ND] f16 + BN partials
// GATHER: A-row m=(b,s,k): first KD/2 from F[b, knn[m], :], second from FC[b, s, :]
// BNA: apply scale/shift + ReLU to A elements on load (f16 in/out)
template <int KD, int ND, bool GATHER, bool BNA, int NPTS, int S>
__global__ __launch_bounds__(256) void gemm_kernel(
    const short* A, const short* FC, const int* KNNp, const short* __restrict__ W,
    const float* __restrict__ bnscale, const float* __restrict__ bnshift,
    short* Hout, float* __restrict__ partials, int M) {
  constexpr int C = KD / 2;
  constexpr int NT = (ND > 128) ? 8 : ND / 16;
  constexpr int BR = (ND > 128) ? 64 : 128;
  constexpr int KT = KD / 32;
  __shared__ short lb[ND * 40];  // [ND][32+8] pad -> <=2-way bank alias on ds_read_b128
  __shared__ float lstats[2 * ND];
  const int tid = threadIdx.x;
  const int wave = tid >> 6, lane = tid & 63;
  const int rowOff = (ND > 128) ? (wave >> 1) * 32 : wave * 32;
  const int colOff = (ND > 128) ? (wave & 1) * 128 : 0;
  const int mBase = blockIdx.x * BR + rowOff;
  for (int i = tid; i < 2 * ND; i += 256) lstats[i] = 0.f;

  const short* aptr[2][2];
#pragma unroll
  for (int rg = 0; rg < 2; ++rg) {
    int m = mBase + rg * 16 + (lane & 15);
    if constexpr (GATHER) {
      int idx = KNNp[m];
      int bb = m / (S * 32);
      int s = (m - bb * (S * 32)) >> 5;
      aptr[rg][0] = A + ((size_t)bb * NPTS + idx) * C;
      aptr[rg][1] = FC + ((size_t)bb * S + s) * C;
    } else {
      aptr[rg][0] = A + (size_t)m * KD;
      aptr[rg][1] = A + (size_t)m * KD + C;
    }
  }
  const int koLane = (lane >> 4) * 8;
  f32x4 acc[2][NT];
#pragma unroll
  for (int rg = 0; rg < 2; ++rg)
#pragma unroll
    for (int nt = 0; nt < NT; ++nt) acc[rg][nt] = (f32x4){0.f, 0.f, 0.f, 0.f};

#pragma unroll
  for (int kt = 0; kt < KT; ++kt) {
    __syncthreads();
    constexpr int CH = (ND * 32) / 2048;
#pragma unroll
    for (int ch = 0; ch < CH; ++ch) {
      int e = ch * 2048 + tid * 8;
      int n = e >> 5, kk = e & 31;
      short8 v = *reinterpret_cast<const short8*>(W + (size_t)n * KD + kt * 32 + kk);
      *reinterpret_cast<short8*>(&lb[n * 40 + kk]) = v;
    }
    __syncthreads();
    const int half = (kt * 32 >= C) ? 1 : 0;
    const int ko = kt * 32 + koLane;
    const int koh = ko - half * C;
    short8 afrag[2];
#pragma unroll
    for (int rg = 0; rg < 2; ++rg) {
      short8 a = *reinterpret_cast<const short8*>(aptr[rg][half] + koh);
      if constexpr (BNA) {
        const float* scp = bnscale + ko;
        const float* shp = bnshift + ko;
#pragma unroll
        for (int j = 0; j < 8; ++j) {
          float v = h2f(a[j]);
          v = fmaxf(v * scp[j] + shp[j], 0.f);
          a[j] = f2h(v);
        }
      }
      afrag[rg] = a;
    }
#pragma unroll
    for (int nt = 0; nt < NT; ++nt) {
      short8 bfr = *reinterpret_cast<const short8*>(&lb[(colOff + nt * 16 + (lane & 15)) * 40 + koLane]);
      acc[0][nt] = mfma16(afrag[0], bfr, acc[0][nt]);
      acc[1][nt] = mfma16(afrag[1], bfr, acc[1][nt]);
    }
  }
  __syncthreads();  // all A-reads done before in-place stores (ND=256 waves share rows)

  // per-channel sum / sumsq partials
#pragma unroll
  for (int nt = 0; nt < NT; ++nt) {
    float s0 = 0.f, s1 = 0.f;
#pragma unroll
    for (int rg = 0; rg < 2; ++rg)
#pragma unroll
      for (int i = 0; i < 4; ++i) {
        float v = acc[rg][nt][i];
        s0 += v; s1 += v * v;
      }
    s0 += __shfl_xor(s0, 16); s0 += __shfl_xor(s0, 32);
    s1 += __shfl_xor(s1, 16); s1 += __shfl_xor(s1, 32);
    if (lane < 16) {
      atomicAdd(&lstats[colOff + nt * 16 + lane], s0);
      atomicAdd(&lstats[ND + colOff + nt * 16 + lane], s1);
    }
  }
  // store output (C/D layout: row = 4*(lane>>4)+i, col = lane&15)
#pragma unroll
  for (int rg = 0; rg < 2; ++rg)
#pragma unroll
    for (int nt = 0; nt < NT; ++nt)
#pragma unroll
      for (int i = 0; i < 4; ++i) {
        int m2 = mBase + rg * 16 + (lane >> 4) * 4 + i;
        int n = colOff + nt * 16 + (lane & 15);
        Hout[(size_t)m2 * ND + n] = f2h(acc[rg][nt][i]);
      }
  __syncthreads();
  for (int i = tid; i < 2 * ND; i += 256)
    partials[(size_t)i * gridDim.x + blockIdx.x] = lstats[i];
}

// ---------- max over K with BN+ReLU -> f1 f16 ----------
__global__ __launch_bounds__(128) void maxpool_f1_kernel(
    const short* __restrict__ h, const float* __restrict__ scale,
    const float* __restrict__ shift, short* __restrict__ f1) {
  const int bs = blockIdx.x, c = threadIdx.x;
  const float sc = scale[c], sh = shift[c];
  float m = 0.f;  // relu outputs >= 0
  for (int k = 0; k < 32; ++k) {
    float v = h2f(h[((size_t)bs * 32 + k) * 128 + c]);
    m = fmaxf(m, fmaxf(v * sc + sh, 0.f));
  }
  f1[(size_t)bs * 128 + c] = f2h(m);
}

// ---------- final: max over K with BN+ReLU, transposed fp32 out [B][C][S] ----------
__global__ __launch_bounds__(256) void maxpool_out_kernel(
    const short* __restrict__ h, const float* __restrict__ scale,
    const float* __restrict__ shift, float* __restrict__ out) {
  const int bs = blockIdx.x, c = threadIdx.x;
  const int b = bs >> 8, s = bs & 255;
  const float sc = scale[c], sh = shift[c];
  float m = 0.f;
  for (int k = 0; k < 32; ++k) {
    float v = h2f(h[((size_t)bs * 32 + k) * 256 + c]);
    m = fmaxf(m, fmaxf(v * sc + sh, 0.f));
  }
  out[((size_t)b << 16) + ((size_t)c << 8) + s] = m;
}

// ---------- launch ----------
extern "C" void kernel_launch(void* const* d_in, const int* in_sizes, int n_in,
                              void* d_out, int out_size, void* d_ws, size_t ws_size,
                              hipStream_t stream) {
  (void)in_sizes; (void)n_in; (void)out_size; (void)ws_size;
  const float* x    = (const float*)d_in[0];
  const float* w1   = (const float*)d_in[1];
  const float* g1   = (const float*)d_in[2];
  const float* b1   = (const float*)d_in[3];
  const float* w2   = (const float*)d_in[4];
  const float* g2   = (const float*)d_in[5];
  const float* b2   = (const float*)d_in[6];
  const float* s1w1 = (const float*)d_in[7];
  const float* s1g1 = (const float*)d_in[8];
  const float* s1b1 = (const float*)d_in[9];
  const float* s1w2 = (const float*)d_in[10];
  const float* s1g2 = (const float*)d_in[11];
  const float* s1b2 = (const float*)d_in[12];
  const float* s2w1 = (const float*)d_in[13];
  const float* s2g1 = (const float*)d_in[14];
  const float* s2b1 = (const float*)d_in[15];
  const float* s2w2 = (const float*)d_in[16];
  const float* s2g2 = (const float*)d_in[17];
  const float* s2b2 = (const float*)d_in[18];
  float* out = (float*)d_out;

  char* ws = (char*)d_ws;
  size_t off = 0;
  auto alloc = [&](size_t bytes) -> char* {
    size_t p = (off + 255) & ~(size_t)255;
    off = p + bytes;
    return ws + p;
  };

  float* xyz      = (float*)alloc(32ull * 4096 * 3 * 4);
  short* h0       = (short*)alloc(32ull * 4096 * 64 * 2);
  short* hb       = (short*)alloc(32ull * 4096 * 64 * 2);
  short* fb       = (short*)alloc(32ull * 4096 * 64 * 2);
  int*   fps1     = (int*)alloc(32ull * 512 * 4);
  float* xyzc1    = (float*)alloc(32ull * 512 * 3 * 4);
  short* fcen1    = (short*)alloc(32ull * 512 * 64 * 2);
  int*   knn1     = (int*)alloc(32ull * 512 * 32 * 4);
  short* f1       = (short*)alloc(32ull * 512 * 128 * 2);
  int*   fps2     = (int*)alloc(32ull * 256 * 4);
  float* xyzc2    = (float*)alloc(32ull * 256 * 3 * 4);
  short* fcen2    = (short*)alloc(32ull * 256 * 128 * 2);
  int*   knn2     = (int*)alloc(32ull * 256 * 32 * 4);
  short* hbuf     = (short*)alloc(134217728ull);          // shared SG1/SG2 h buffer
  float* partials = (float*)alloc(2ull * 256 * 4096 * 4); // 8 MB
  float* totals   = (float*)alloc(512 * 4);
  float* scA  = (float*)alloc(64 * 4);  float* shA  = (float*)alloc(64 * 4);
  float* scBc = (float*)alloc(64 * 4);  float* shBc = (float*)alloc(64 * 4);
  float* sc1a = (float*)alloc(128 * 4); float* sh1a = (float*)alloc(128 * 4);
  float* sc1b = (float*)alloc(128 * 4); float* sh1b = (float*)alloc(128 * 4);
  float* sc2a = (float*)alloc(256 * 4); float* sh2a = (float*)alloc(256 * 4);
  float* sc2b = (float*)alloc(256 * 4); float* sh2b = (float*)alloc(256 * 4);
  short* w2b   = (short*)alloc(4096 * 2);
  short* s1w2b = (short*)alloc(16384 * 2);
  short* s2w2b = (short*)alloc(65536 * 2);
  short* W1pp  = (short*)alloc(16384 * 2);
  short* W2pp  = (short*)alloc(65536 * 2);

  prep_kernel<<<656, 256, 0, stream>>>(w2, s1w2, s2w2, s1w1, s2w1, w2b, s1w2b, s2w2b, W1pp, W2pp);
  stageA_kernel<<<512, 256, 0, stream>>>(x, w1, xyz, h0);
  stats64_kernel<<<256, 256, 0, stream>>>(h0, partials, 131072);
  reduce_kernel<<<128, 256, 0, stream>>>(partials, totals, 256);
  finalize_kernel<<<1, 64, 0, stream>>>(totals, g1, b1, scA, shA, 64, 1.f / 131072.f);
  gemm_kernel<64, 64, false, true, 1, 1><<<1024, 256, 0, stream>>>(
      h0, nullptr, nullptr, w2b, scA, shA, hb, partials, 131072);
  reduce_kernel<<<128, 256, 0, stream>>>(partials, totals, 1024);
  finalize_kernel<<<1, 64, 0, stream>>>(totals, g2, b2, scBc, shBc, 64, 1.f / 131072.f);
  apply_kernel<<<4096, 256, 0, stream>>>(hb, fb, scBc, shBc, 1048576, 63);

  fps_kernel<4096, 1024><<<32, 1024, 0, stream>>>(xyz, fps1, 512);
  gather_kernel<512, 4096, 64><<<16384, 64, 0, stream>>>(fps1, xyz, fb, xyzc1, fcen1);
  knn_kernel<4096, 512><<<16384, 256, 0, stream>>>(xyz, xyzc1, knn1);

  gemm_kernel<128, 128, true, false, 4096, 512><<<4096, 256, 0, stream>>>(
      fb, fcen1, knn1, W1pp, nullptr, nullptr, hbuf, partials, 524288);
  reduce_kernel<<<256, 256, 0, stream>>>(partials, totals, 4096);
  finalize_kernel<<<1, 128, 0, stream>>>(totals, s1g1, s1b1, sc1a, sh1a, 128, 1.f / 524288.f);
  gemm_kernel<128, 128, false, true, 1, 1><<<4096, 256, 0, stream>>>(
      hbuf, nullptr, nullptr, s1w2b, sc1a, sh1a, hbuf, partials, 524288);
  reduce_kernel<<<256, 256, 0, stream>>>(partials, totals, 4096);
  finalize_kernel<<<1, 128, 0, stream>>>(totals, s1g2, s1b2, sc1b, sh1b, 128, 1.f / 524288.f);
  maxpool_f1_kernel<<<16384, 128, 0, stream>>>(hbuf, sc1b, sh1b, f1);

  fps_kernel<512, 512><<<32, 512, 0, stream>>>(xyzc1, fps2, 256);
  gather_kernel<256, 512, 128><<<8192, 128, 0, stream>>>(fps2, xyzc1, f1, xyzc2, fcen2);
  knn_kernel<512, 256><<<8192, 256, 0, stream>>>(xyzc1, xyzc2, knn2);

  gemm_kernel<256, 256, true, false, 512, 256><<<4096, 256, 0, stream>>>(
      f1, fcen2, knn2, W2pp, nullptr, nullptr, hbuf, partials, 262144);
  reduce_kernel<<<512, 256, 0, stream>>>(partials, totals, 4096);
  finalize_kernel<<<1, 256, 0, stream>>>(totals, s2g1, s2b1, sc2a, sh2a, 256, 1.f / 262144.f);
  gemm_kernel<256, 256, false, true, 1, 1><<<4096, 256, 0, stream>>>(
      hbuf, nullptr, nullptr, s2w2b, sc2a, sh2a, hbuf, partials, 262144);
  reduce_kernel<<<512, 256, 0, stream>>>(partials, totals, 4096);
  finalize_kernel<<<1, 256, 0, stream>>>(totals, s2g2, s2b2, sc2b, sh2b, 256, 1.f / 262144.f);
  maxpool_out_kernel<<<8192, 256, 0, stream>>>(hbuf, sc2b, sh2b, out);
}

// Round 5
// 1472.592 us; speedup vs baseline: 1.3365x; 1.1617x over previous
//
#include <hip/hip_runtime.h>

// ---------- types & helpers ----------
typedef short short8 __attribute__((ext_vector_type(8)));
typedef _Float16 h8 __attribute__((ext_vector_type(8)));
typedef float f32x4 __attribute__((ext_vector_type(4)));

#define DEVI __device__ __forceinline__

DEVI float h2f(short s) { return (float)__builtin_bit_cast(_Float16, s); }
DEVI short f2h(float f) { return __builtin_bit_cast(short, (_Float16)f); }
DEVI f32x4 mfma16(short8 a, short8 b, f32x4 c) {
  return __builtin_amdgcn_mfma_f32_16x16x32_f16(
      __builtin_bit_cast(h8, a), __builtin_bit_cast(h8, b), c, 0, 0, 0);
}

// ---------- DPP 64-lane reductions (gfx9 pattern), result broadcast ----------
DEVI float wave_max_bcast(float v) {
  const int ID = 0xff800000;  // -inf
  int x = __builtin_bit_cast(int, v);
#define STEPM(ctrl)                                                     \
  {                                                                     \
    int t = __builtin_amdgcn_update_dpp(ID, x, ctrl, 0xf, 0xf, false);  \
    x = __builtin_bit_cast(int, fmaxf(__builtin_bit_cast(float, x),     \
                                      __builtin_bit_cast(float, t)));   \
  }
  STEPM(0x111) STEPM(0x112) STEPM(0x114) STEPM(0x118) STEPM(0x142) STEPM(0x143)
#undef STEPM
  return __builtin_bit_cast(float, __builtin_amdgcn_readlane(x, 63));
}
DEVI float wave_min_bcast_f(float v) {
  const int ID = 0x7f800000;  // +inf
  int x = __builtin_bit_cast(int, v);
#define STEPN(ctrl)                                                     \
  {                                                                     \
    int t = __builtin_amdgcn_update_dpp(ID, x, ctrl, 0xf, 0xf, false);  \
    x = __builtin_bit_cast(int, fminf(__builtin_bit_cast(float, x),     \
                                      __builtin_bit_cast(float, t)));   \
  }
  STEPN(0x111) STEPN(0x112) STEPN(0x114) STEPN(0x118) STEPN(0x142) STEPN(0x143)
#undef STEPN
  return __builtin_bit_cast(float, __builtin_amdgcn_readlane(x, 63));
}
DEVI unsigned wave_min_bcast_u(unsigned v) {
  const int ID = (int)0xffffffff;
  int x = (int)v;
#define STEPU(ctrl)                                                     \
  {                                                                     \
    int t = __builtin_amdgcn_update_dpp(ID, x, ctrl, 0xf, 0xf, false);  \
    x = (int)((unsigned)x < (unsigned)t ? (unsigned)x : (unsigned)t);   \
  }
  STEPU(0x111) STEPU(0x112) STEPU(0x114) STEPU(0x118) STEPU(0x142) STEPU(0x143)
#undef STEPU
  return (unsigned)__builtin_amdgcn_readlane(x, 63);
}

// ---------- weight prep: f16 casts + folded W'' = [w1a | w1b - w1a] ----------
__global__ __launch_bounds__(256) void prep_kernel(
    const float* __restrict__ w2, const float* __restrict__ s1w2,
    const float* __restrict__ s2w2, const float* __restrict__ s1w1,
    const float* __restrict__ s2w1, short* __restrict__ w2b,
    short* __restrict__ s1w2b, short* __restrict__ s2w2b,
    short* __restrict__ W1pp, short* __restrict__ W2pp) {
  int i = blockIdx.x * 256 + threadIdx.x;
  if (i < 4096) {
    w2b[i] = f2h(w2[i]);
  } else if (i < 20480) {
    int j = i - 4096; s1w2b[j] = f2h(s1w2[j]);
  } else if (i < 86016) {
    int j = i - 20480; s2w2b[j] = f2h(s2w2[j]);
  } else if (i < 102400) {
    int j = i - 86016; int c = j & 127;
    float v = s1w1[j]; if (c >= 64) v -= s1w1[j - 64];
    W1pp[j] = f2h(v);
  } else if (i < 167936) {
    int j = i - 102400; int c = j & 255;
    float v = s2w1[j]; if (c >= 128) v -= s2w1[j - 128];
    W2pp[j] = f2h(v);
  }
}

// ---------- stage A: xyz transpose + h0 = x @ w1^T (K=3, VALU fp32) ----------
__global__ __launch_bounds__(256) void stageA_kernel(
    const float* __restrict__ x, const float* __restrict__ w1,
    float* __restrict__ xyz, short* __restrict__ h0) {
  int i = blockIdx.x * 256 + threadIdx.x;  // b*4096 + n, < 131072
  int b = i >> 12, n = i & 4095;
  const float* xb = x + ((size_t)b * 3 << 12) + n;
  float x0 = xb[0], x1 = xb[4096], x2 = xb[8192];
  float* xp = xyz + (size_t)i * 3;
  xp[0] = x0; xp[1] = x1; xp[2] = x2;
  short* hp = h0 + ((size_t)i << 6);
#pragma unroll
  for (int o8 = 0; o8 < 8; ++o8) {
    short8 t;
#pragma unroll
    for (int j = 0; j < 8; ++j) {
      int o = o8 * 8 + j;
      float h = x0 * w1[o * 3] + x1 * w1[o * 3 + 1] + x2 * w1[o * 3 + 2];
      t[j] = f2h(h);
    }
    *reinterpret_cast<short8*>(hp + o8 * 8) = t;
  }
}

// ---------- channel stats for a [M][64] f16 tensor -> transposed partials ----------
__global__ __launch_bounds__(256) void stats64_kernel(
    const short* __restrict__ h, float* __restrict__ partials, int M) {
  __shared__ float l0[256], l1[256];
  const int tid = threadIdx.x;
  const int c = tid & 63, g = tid >> 6;
  float s0 = 0.f, s1 = 0.f;
  for (int m = blockIdx.x * 4 + g; m < M; m += gridDim.x * 4) {
    float v = h2f(h[(size_t)m * 64 + c]);
    s0 += v; s1 += v * v;
  }
  l0[tid] = s0; l1[tid] = s1;
  __syncthreads();
  if (g == 0) {
    for (int w = 1; w < 4; ++w) { s0 += l0[c + w * 64]; s1 += l1[c + w * 64]; }
    partials[(size_t)c * gridDim.x + blockIdx.x] = s0;
    partials[(size_t)(64 + c) * gridDim.x + blockIdx.x] = s1;
  }
}

// ---------- reduce partials[j][0..NB) -> totals[j] ----------
__global__ __launch_bounds__(256) void reduce_kernel(
    const float* __restrict__ partials, float* __restrict__ totals, int NB) {
  __shared__ float l[4];
  const int j = blockIdx.x, tid = threadIdx.x;
  float s = 0.f;
  for (int i = tid; i < NB; i += 256) s += partials[(size_t)j * NB + i];
#pragma unroll
  for (int off = 1; off < 64; off <<= 1) s += __shfl_xor(s, off);
  if ((tid & 63) == 0) l[tid >> 6] = s;
  __syncthreads();
  if (tid == 0) totals[j] = l[0] + l[1] + l[2] + l[3];
}

// ---------- finalize BN: scale = g*rsqrt(var+eps), shift = b - mean*scale ----------
__global__ void finalize_kernel(const float* __restrict__ totals,
                                const float* __restrict__ gamma,
                                const float* __restrict__ beta,
                                float* __restrict__ scale, float* __restrict__ shift,
                                int C, float invM) {
  int c = threadIdx.x;
  if (c < C) {
    float mean = totals[c] * invM;
    float var = totals[C + c] * invM - mean * mean;
    var = fmaxf(var, 0.f);
    float sc = gamma[c] / sqrtf(var + 1e-5f);
    scale[c] = sc;
    shift[c] = beta[c] - mean * sc;
  }
}

// ---------- elementwise BN+ReLU apply (f16 -> f16), 8 elems/thread ----------
__global__ __launch_bounds__(256) void apply_kernel(
    const short* __restrict__ h, short* __restrict__ f,
    const float* __restrict__ scale, const float* __restrict__ shift,
    int total8, int Cmask) {
  int t = blockIdx.x * 256 + threadIdx.x;
  if (t >= total8) return;
  size_t i = (size_t)t * 8;
  int c0 = (int)(i & (size_t)Cmask);
  short8 v = *reinterpret_cast<const short8*>(h + i);
  short8 o;
#pragma unroll
  for (int j = 0; j < 8; ++j) {
    float y = h2f(v[j]) * scale[c0 + j] + shift[c0 + j];
    o[j] = f2h(fmaxf(y, 0.f));
  }
  *reinterpret_cast<short8*>(f + i) = o;
}

// ---------- farthest point sampling v4 ----------
// T=256 (4 waves): reduce work is per-wave-replicated, so fewer waves beat more.
// Value-only fmin/fmax update; index rescan; wave DPP argmax; cross-wave
// combine carries (v,idx) only; winner coords via ONE broadcast LDS read.
// One barrier per iteration (double-buffered slots). Exact numpy tie-break.
template <int NPTS, int T>
__global__ __launch_bounds__(T) void fps_kernel(const float* __restrict__ xyz,
                                                int* __restrict__ out, int nsel) {
  constexpr int PT = NPTS / T;
  constexpr int NW = T / 64;
  __shared__ float sx[NPTS], sy[NPTS], sz[NPTS];
  __shared__ float wv[2][NW];
  __shared__ unsigned wi[2][NW];
  const int tid = threadIdx.x, b = blockIdx.x;
  const int lane = tid & 63, wave = tid >> 6;
  const float* base = xyz + (size_t)b * NPTS * 3;
  float px[PT], py[PT], pz[PT], dmin[PT];
#pragma unroll
  for (int j = 0; j < PT; ++j) {
    int n = j * T + tid;
    px[j] = base[n * 3]; py[j] = base[n * 3 + 1]; pz[j] = base[n * 3 + 2];
    sx[n] = px[j]; sy[n] = py[j]; sz[n] = pz[j];
    dmin[j] = 1e10f;
  }
  __syncthreads();
  int far = 0;
  float cx = sx[0], cy = sy[0], cz = sz[0];
  for (int it = 0; it < nsel; ++it) {
    if (tid == 0) out[b * nsel + it] = far;
    float bv = -1.f;
#pragma unroll
    for (int j = 0; j < PT; ++j) {
      float dx = __fsub_rn(px[j], cx), dy = __fsub_rn(py[j], cy), dz = __fsub_rn(pz[j], cz);
      float d = __fadd_rn(__fadd_rn(__fmul_rn(dx, dx), __fmul_rn(dy, dy)), __fmul_rn(dz, dz));
      float dm = fminf(dmin[j], d);
      dmin[j] = dm;
      bv = fmaxf(bv, dm);
    }
    float wmv = wave_max_bcast(bv);
    // rescan (descending j so the LAST write = smallest index)
    unsigned ci = 0xffffffffu;
#pragma unroll
    for (int j = PT - 1; j >= 0; --j)
      if (dmin[j] == wmv) ci = (unsigned)(j * T + tid);
    unsigned wmi = wave_min_bcast_u(ci);
    const int bsel = it & 1;
    if (lane == 0) { wv[bsel][wave] = wmv; wi[bsel][wave] = wmi; }
    __syncthreads();
    // lane-parallel cross-wave combine: lane reads slot (lane & (NW-1)),
    // then log2(NW) DPP row_ror steps carrying (v, idx).
    const int e = lane & (NW - 1);
    float v = wv[bsel][e];
    unsigned si = wi[bsel][e];
#define CMB(ctrl)                                                                        \
  {                                                                                      \
    float v2 = __builtin_bit_cast(                                                       \
        float, __builtin_amdgcn_update_dpp(0, __builtin_bit_cast(int, v), ctrl, 0xf, 0xf, true)); \
    unsigned i2 = (unsigned)__builtin_amdgcn_update_dpp(0, (int)si, ctrl, 0xf, 0xf, true);\
    bool bt = (v2 > v) || (v2 == v && i2 < si);                                          \
    v = bt ? v2 : v; si = bt ? i2 : si;                                                  \
  }
    if constexpr (NW >= 2) CMB(0x121)   // row_ror:1
    if constexpr (NW >= 4) CMB(0x122)   // row_ror:2
    if constexpr (NW >= 8) CMB(0x124)   // row_ror:4
    if constexpr (NW >= 16) CMB(0x128)  // row_ror:8
#undef CMB
    far = (int)si;
    cx = sx[far]; cy = sy[far]; cz = sz[far];  // broadcast LDS read, once/iter
  }
}

// ---------- kNN: 32 smallest (d, idx) per center; DPP argmin + incremental local min
template <int NPTS, int S>
__global__ __launch_bounds__(256) void knn_kernel(const float* __restrict__ pts,
                                                  const float* __restrict__ ctr,
                                                  int* __restrict__ knn) {
  constexpr int PT = NPTS / 256;
  __shared__ float wv[2][4];
  __shared__ unsigned wi[2][4];
  const int tid = threadIdx.x, bs = blockIdx.x;
  const int lane = tid & 63, wave = tid >> 6;
  const int b = bs / S;
  const float* base = pts + (size_t)b * NPTS * 3;
  const float qx = ctr[bs * 3], qy = ctr[bs * 3 + 1], qz = ctr[bs * 3 + 2];
  const float qq = __fadd_rn(__fadd_rn(__fmul_rn(qx, qx), __fmul_rn(qy, qy)), __fmul_rn(qz, qz));
  float d[PT];
#pragma unroll
  for (int j = 0; j < PT; ++j) {
    int n = j * 256 + tid;
    float x = base[n * 3], y = base[n * 3 + 1], z = base[n * 3 + 2];
    float pp = __fadd_rn(__fadd_rn(__fmul_rn(x, x), __fmul_rn(y, y)), __fmul_rn(z, z));
    float dot = __fadd_rn(__fadd_rn(__fmul_rn(qx, x), __fmul_rn(qy, y)), __fmul_rn(qz, z));
    d[j] = __fsub_rn(__fadd_rn(qq, pp), __fmul_rn(2.f, dot));
  }
  unsigned sel = 0;
  float bv = 3.4e38f; unsigned bi = 0x7fffffffu;
#pragma unroll
  for (int j = 0; j < PT; ++j)
    if (d[j] < bv) { bv = d[j]; bi = (unsigned)(j * 256 + tid); }
  for (int k = 0; k < 32; ++k) {
    float wmv = wave_min_bcast_f(bv);
    unsigned ci = (bv == wmv) ? bi : 0x7fffffffu;
    unsigned wmi = wave_min_bcast_u(ci);
    if (lane == 0) { wv[k & 1][wave] = wmv; wi[k & 1][wave] = wmi; }
    __syncthreads();
    float gv = wv[k & 1][0]; unsigned gi = wi[k & 1][0];
#pragma unroll
    for (int w = 1; w < 4; ++w) {
      float ov = wv[k & 1][w]; unsigned oi = wi[k & 1][w];
      if (ov < gv || (ov == gv && oi < gi)) { gv = ov; gi = oi; }
    }
    if (tid == 0) knn[(size_t)bs * 32 + k] = (int)gi;
    if ((gi & 255u) == (unsigned)tid) {  // only the winner rescans its candidates
      sel |= 1u << (gi >> 8);
      bv = 3.4e38f; bi = 0x7fffffffu;
#pragma unroll
      for (int j = 0; j < PT; ++j)
        if (!((sel >> j) & 1u) && d[j] < bv) { bv = d[j]; bi = (unsigned)(j * 256 + tid); }
    }
  }
}

// ---------- gather centers: xyz + features at fps indices ----------
template <int S, int NPTS, int C>
__global__ void gather_kernel(const int* __restrict__ fps, const float* __restrict__ xyzsrc,
                              const short* __restrict__ fsrc, float* __restrict__ xyzdst,
                              short* __restrict__ fdst) {
  const int bs = blockIdx.x, tid = threadIdx.x;
  const int b = bs / S;
  const int idx = fps[bs];
  fdst[(size_t)bs * C + tid] = fsrc[((size_t)b * NPTS + idx) * C + tid];
  if (tid < 3) xyzdst[(size_t)bs * 3 + tid] = xyzsrc[((size_t)b * NPTS + idx) * 3 + tid];
}

// ---------- MFMA GEMM: [M][KD] @ [ND][KD]^T -> [M][ND] f16 + BN partials
// GATHER: A-row m=(b,s,k): first KD/2 from F[b, knn[m], :], second from FC[b, s, :]
// BNA: apply scale/shift + ReLU to A elements on load (f16 in/out)
template <int KD, int ND, bool GATHER, bool BNA, int NPTS, int S>
__global__ __launch_bounds__(256) void gemm_kernel(
    const short* A, const short* FC, const int* KNNp, const short* __restrict__ W,
    const float* __restrict__ bnscale, const float* __restrict__ bnshift,
    short* Hout, float* __restrict__ partials, int M) {
  constexpr int C = KD / 2;
  constexpr int NT = (ND > 128) ? 8 : ND / 16;
  constexpr int BR = (ND > 128) ? 64 : 128;
  constexpr int KT = KD / 32;
  __shared__ short lb[ND * 40];  // [ND][32+8] pad -> <=2-way bank alias on ds_read_b128
  __shared__ float lstats[2 * ND];
  const int tid = threadIdx.x;
  const int wave = tid >> 6, lane = tid & 63;
  const int rowOff = (ND > 128) ? (wave >> 1) * 32 : wave * 32;
  const int colOff = (ND > 128) ? (wave & 1) * 128 : 0;
  const int mBase = blockIdx.x * BR + rowOff;
  for (int i = tid; i < 2 * ND; i += 256) lstats[i] = 0.f;

  const short* aptr[2][2];
#pragma unroll
  for (int rg = 0; rg < 2; ++rg) {
    int m = mBase + rg * 16 + (lane & 15);
    if constexpr (GATHER) {
      int idx = KNNp[m];
      int bb = m / (S * 32);
      int s = (m - bb * (S * 32)) >> 5;
      aptr[rg][0] = A + ((size_t)bb * NPTS + idx) * C;
      aptr[rg][1] = FC + ((size_t)bb * S + s) * C;
    } else {
      aptr[rg][0] = A + (size_t)m * KD;
      aptr[rg][1] = A + (size_t)m * KD + C;
    }
  }
  const int koLane = (lane >> 4) * 8;
  f32x4 acc[2][NT];
#pragma unroll
  for (int rg = 0; rg < 2; ++rg)
#pragma unroll
    for (int nt = 0; nt < NT; ++nt) acc[rg][nt] = (f32x4){0.f, 0.f, 0.f, 0.f};

#pragma unroll
  for (int kt = 0; kt < KT; ++kt) {
    __syncthreads();
    constexpr int CH = (ND * 32) / 2048;
#pragma unroll
    for (int ch = 0; ch < CH; ++ch) {
      int e = ch * 2048 + tid * 8;
      int n = e >> 5, kk = e & 31;
      short8 v = *reinterpret_cast<const short8*>(W + (size_t)n * KD + kt * 32 + kk);
      *reinterpret_cast<short8*>(&lb[n * 40 + kk]) = v;
    }
    __syncthreads();
    const int half = (kt * 32 >= C) ? 1 : 0;
    const int ko = kt * 32 + koLane;
    const int koh = ko - half * C;
    short8 afrag[2];
#pragma unroll
    for (int rg = 0; rg < 2; ++rg) {
      short8 a = *reinterpret_cast<const short8*>(aptr[rg][half] + koh);
      if constexpr (BNA) {
        const float* scp = bnscale + ko;
        const float* shp = bnshift + ko;
#pragma unroll
        for (int j = 0; j < 8; ++j) {
          float v = h2f(a[j]);
          v = fmaxf(v * scp[j] + shp[j], 0.f);
          a[j] = f2h(v);
        }
      }
      afrag[rg] = a;
    }
#pragma unroll
    for (int nt = 0; nt < NT; ++nt) {
      short8 bfr = *reinterpret_cast<const short8*>(&lb[(colOff + nt * 16 + (lane & 15)) * 40 + koLane]);
      acc[0][nt] = mfma16(afrag[0], bfr, acc[0][nt]);
      acc[1][nt] = mfma16(afrag[1], bfr, acc[1][nt]);
    }
  }
  __syncthreads();  // all A-reads done before in-place stores (ND=256 waves share rows)

  // per-channel sum / sumsq partials
#pragma unroll
  for (int nt = 0; nt < NT; ++nt) {
    float s0 = 0.f, s1 = 0.f;
#pragma unroll
    for (int rg = 0; rg < 2; ++rg)
#pragma unroll
      for (int i = 0; i < 4; ++i) {
        float v = acc[rg][nt][i];
        s0 += v; s1 += v * v;
      }
    s0 += __shfl_xor(s0, 16); s0 += __shfl_xor(s0, 32);
    s1 += __shfl_xor(s1, 16); s1 += __shfl_xor(s1, 32);
    if (lane < 16) {
      atomicAdd(&lstats[colOff + nt * 16 + lane], s0);
      atomicAdd(&lstats[ND + colOff + nt * 16 + lane], s1);
    }
  }
  // store output (C/D layout: row = 4*(lane>>4)+i, col = lane&15)
#pragma unroll
  for (int rg = 0; rg < 2; ++rg)
#pragma unroll
    for (int nt = 0; nt < NT; ++nt)
#pragma unroll
      for (int i = 0; i < 4; ++i) {
        int m2 = mBase + rg * 16 + (lane >> 4) * 4 + i;
        int n = colOff + nt * 16 + (lane & 15);
        Hout[(size_t)m2 * ND + n] = f2h(acc[rg][nt][i]);
      }
  __syncthreads();
  for (int i = tid; i < 2 * ND; i += 256)
    partials[(size_t)i * gridDim.x + blockIdx.x] = lstats[i];
}

// ---------- max over K with BN+ReLU -> f1 f16 ----------
__global__ __launch_bounds__(128) void maxpool_f1_kernel(
    const short* __restrict__ h, const float* __restrict__ scale,
    const float* __restrict__ shift, short* __restrict__ f1) {
  const int bs = blockIdx.x, c = threadIdx.x;
  const float sc = scale[c], sh = shift[c];
  float m = 0.f;  // relu outputs >= 0
  for (int k = 0; k < 32; ++k) {
    float v = h2f(h[((size_t)bs * 32 + k) * 128 + c]);
    m = fmaxf(m, fmaxf(v * sc + sh, 0.f));
  }
  f1[(size_t)bs * 128 + c] = f2h(m);
}

// ---------- final: max over K with BN+ReLU, transposed fp32 out [B][C][S] ----------
__global__ __launch_bounds__(256) void maxpool_out_kernel(
    const short* __restrict__ h, const float* __restrict__ scale,
    const float* __restrict__ shift, float* __restrict__ out) {
  const int bs = blockIdx.x, c = threadIdx.x;
  const int b = bs >> 8, s = bs & 255;
  const float sc = scale[c], sh = shift[c];
  float m = 0.f;
  for (int k = 0; k < 32; ++k) {
    float v = h2f(h[((size_t)bs * 32 + k) * 256 + c]);
    m = fmaxf(m, fmaxf(v * sc + sh, 0.f));
  }
  out[((size_t)b << 16) + ((size_t)c << 8) + s] = m;
}

// ---------- launch ----------
extern "C" void kernel_launch(void* const* d_in, const int* in_sizes, int n_in,
                              void* d_out, int out_size, void* d_ws, size_t ws_size,
                              hipStream_t stream) {
  (void)in_sizes; (void)n_in; (void)out_size; (void)ws_size;
  const float* x    = (const float*)d_in[0];
  const float* w1   = (const float*)d_in[1];
  const float* g1   = (const float*)d_in[2];
  const float* b1   = (const float*)d_in[3];
  const float* w2   = (const float*)d_in[4];
  const float* g2   = (const float*)d_in[5];
  const float* b2   = (const float*)d_in[6];
  const float* s1w1 = (const float*)d_in[7];
  const float* s1g1 = (const float*)d_in[8];
  const float* s1b1 = (const float*)d_in[9];
  const float* s1w2 = (const float*)d_in[10];
  const float* s1g2 = (const float*)d_in[11];
  const float* s1b2 = (const float*)d_in[12];
  const float* s2w1 = (const float*)d_in[13];
  const float* s2g1 = (const float*)d_in[14];
  const float* s2b1 = (const float*)d_in[15];
  const float* s2w2 = (const float*)d_in[16];
  const float* s2g2 = (const float*)d_in[17];
  const float* s2b2 = (const float*)d_in[18];
  float* out = (float*)d_out;

  char* ws = (char*)d_ws;
  size_t off = 0;
  auto alloc = [&](size_t bytes) -> char* {
    size_t p = (off + 255) & ~(size_t)255;
    off = p + bytes;
    return ws + p;
  };

  float* xyz      = (float*)alloc(32ull * 4096 * 3 * 4);
  short* h0       = (short*)alloc(32ull * 4096 * 64 * 2);
  short* hb       = (short*)alloc(32ull * 4096 * 64 * 2);
  short* fb       = (short*)alloc(32ull * 4096 * 64 * 2);
  int*   fps1     = (int*)alloc(32ull * 512 * 4);
  float* xyzc1    = (float*)alloc(32ull * 512 * 3 * 4);
  short* fcen1    = (short*)alloc(32ull * 512 * 64 * 2);
  int*   knn1     = (int*)alloc(32ull * 512 * 32 * 4);
  short* f1       = (short*)alloc(32ull * 512 * 128 * 2);
  int*   fps2     = (int*)alloc(32ull * 256 * 4);
  float* xyzc2    = (float*)alloc(32ull * 256 * 3 * 4);
  short* fcen2    = (short*)alloc(32ull * 256 * 128 * 2);
  int*   knn2     = (int*)alloc(32ull * 256 * 32 * 4);
  short* hbuf     = (short*)alloc(134217728ull);          // shared SG1/SG2 h buffer
  float* partials = (float*)alloc(2ull * 256 * 4096 * 4); // 8 MB
  float* totals   = (float*)alloc(512 * 4);
  float* scA  = (float*)alloc(64 * 4);  float* shA  = (float*)alloc(64 * 4);
  float* scBc = (float*)alloc(64 * 4);  float* shBc = (float*)alloc(64 * 4);
  float* sc1a = (float*)alloc(128 * 4); float* sh1a = (float*)alloc(128 * 4);
  float* sc1b = (float*)alloc(128 * 4); float* sh1b = (float*)alloc(128 * 4);
  float* sc2a = (float*)alloc(256 * 4); float* sh2a = (float*)alloc(256 * 4);
  float* sc2b = (float*)alloc(256 * 4); float* sh2b = (float*)alloc(256 * 4);
  short* w2b   = (short*)alloc(4096 * 2);
  short* s1w2b = (short*)alloc(16384 * 2);
  short* s2w2b = (short*)alloc(65536 * 2);
  short* W1pp  = (short*)alloc(16384 * 2);
  short* W2pp  = (short*)alloc(65536 * 2);

  prep_kernel<<<656, 256, 0, stream>>>(w2, s1w2, s2w2, s1w1, s2w1, w2b, s1w2b, s2w2b, W1pp, W2pp);
  stageA_kernel<<<512, 256, 0, stream>>>(x, w1, xyz, h0);
  stats64_kernel<<<256, 256, 0, stream>>>(h0, partials, 131072);
  reduce_kernel<<<128, 256, 0, stream>>>(partials, totals, 256);
  finalize_kernel<<<1, 64, 0, stream>>>(totals, g1, b1, scA, shA, 64, 1.f / 131072.f);
  gemm_kernel<64, 64, false, true, 1, 1><<<1024, 256, 0, stream>>>(
      h0, nullptr, nullptr, w2b, scA, shA, hb, partials, 131072);
  reduce_kernel<<<128, 256, 0, stream>>>(partials, totals, 1024);
  finalize_kernel<<<1, 64, 0, stream>>>(totals, g2, b2, scBc, shBc, 64, 1.f / 131072.f);
  apply_kernel<<<4096, 256, 0, stream>>>(hb, fb, scBc, shBc, 1048576, 63);

  fps_kernel<4096, 256><<<32, 256, 0, stream>>>(xyz, fps1, 512);
  gather_kernel<512, 4096, 64><<<16384, 64, 0, stream>>>(fps1, xyz, fb, xyzc1, fcen1);
  knn_kernel<4096, 512><<<16384, 256, 0, stream>>>(xyz, xyzc1, knn1);

  gemm_kernel<128, 128, true, false, 4096, 512><<<4096, 256, 0, stream>>>(
      fb, fcen1, knn1, W1pp, nullptr, nullptr, hbuf, partials, 524288);
  reduce_kernel<<<256, 256, 0, stream>>>(partials, totals, 4096);
  finalize_kernel<<<1, 128, 0, stream>>>(totals, s1g1, s1b1, sc1a, sh1a, 128, 1.f / 524288.f);
  gemm_kernel<128, 128, false, true, 1, 1><<<4096, 256, 0, stream>>>(
      hbuf, nullptr, nullptr, s1w2b, sc1a, sh1a, hbuf, partials, 524288);
  reduce_kernel<<<256, 256, 0, stream>>>(partials, totals, 4096);
  finalize_kernel<<<1, 128, 0, stream>>>(totals, s1g2, s1b2, sc1b, sh1b, 128, 1.f / 524288.f);
  maxpool_f1_kernel<<<16384, 128, 0, stream>>>(hbuf, sc1b, sh1b, f1);

  fps_kernel<512, 256><<<32, 256, 0, stream>>>(xyzc1, fps2, 256);
  gather_kernel<256, 512, 128><<<8192, 128, 0, stream>>>(fps2, xyzc1, f1, xyzc2, fcen2);
  knn_kernel<512, 256><<<8192, 256, 0, stream>>>(xyzc1, xyzc2, knn2);

  gemm_kernel<256, 256, true, false, 512, 256><<<4096, 256, 0, stream>>>(
      f1, fcen2, knn2, W2pp, nullptr, nullptr, hbuf, partials, 262144);
  reduce_kernel<<<512, 256, 0, stream>>>(partials, totals, 4096);
  finalize_kernel<<<1, 256, 0, stream>>>(totals, s2g1, s2b1, sc2a, sh2a, 256, 1.f / 262144.f);
  gemm_kernel<256, 256, false, true, 1, 1><<<4096, 256, 0, stream>>>(
      hbuf, nullptr, nullptr, s2w2b, sc2a, sh2a, hbuf, partials, 262144);
  reduce_kernel<<<512, 256, 0, stream>>>(partials, totals, 4096);
  finalize_kernel<<<1, 256, 0, stream>>>(totals, s2g2, s2b2, sc2b, sh2b, 256, 1.f / 262144.f);
  maxpool_out_kernel<<<8192, 256, 0, stream>>>(hbuf, sc2b, sh2b, out);
}